// Round 5
// baseline (3121.997 us; speedup 1.0000x reference)
//
#include <hip/hip_runtime.h>

// EMA codebook update (VQ-VAE), MI355X. fp16-MFMA distance filter + exact
// fp32 rescore for near-ties. N=32768, K=8192, D=256.
// R5: fast tiled resolve (4-acc ILP, K-split, LDS row staging); DELTA 0.3.

#define DECAY 0.99f
#define OMD 0.01f
#define EPS 1e-5f
#define DELTA 0.3f

constexpr int N = 32768, K = 8192, D = 256;
constexpr int KSPLIT = 2;               // gemm grid: 128 row-tiles x 2 code-splits
constexpr int BMt = 256, BNt = 128;     // gemm tile
constexpr int GT = 512;                 // gemm threads (8 waves)

// resolve config
constexpr int RGRP = 64;                // flagged rows per group
constexpr int RKS = 8;                  // K splits (1024 codes each)
constexpr int RGW = 32;                 // group-slot width (grid = RGW*RKS)

typedef _Float16 f16x8 __attribute__((ext_vector_type(8)));
typedef float f32x4 __attribute__((ext_vector_type(4)));

// d_out layout (floats, reference return order)
constexpr long Q_OFF   = 0;
constexpr long IDX_OFF = (long)N * D;
constexpr long CB_OFF  = IDX_OFF + N;
constexpr long EMB_OFF = CB_OFF + (long)K * D;
constexpr long CS_OFF  = EMB_OFF + (long)K * D;

// ws layout (bytes)
constexpr long WS_TOPS = 0;                          // ulonglong2[N*KSPLIT]
constexpr long WS_RES  = WS_TOPS + (long)N * 2 * 16; // u64[N] resolved
constexpr long WS_IDX  = WS_RES + (long)N * 8;       // int[N]
constexpr long WS_C2   = WS_IDX + (long)N * 4;       // float[K]
constexpr long WS_FLAG = WS_C2 + (long)K * 4;        // int[N] flagged rows
constexpr long WS_CNT  = WS_FLAG + (long)N * 4;      // [0] u32 count, [1] f32 nacc

__device__ inline unsigned transScore(float s) {
    unsigned u = __float_as_uint(s);
    return u ^ ((unsigned)((int)u >> 31) | 0x80000000u);   // order-preserving
}
__device__ inline float untransScore(unsigned u) {
    return (u & 0x80000000u) ? __uint_as_float(u ^ 0x80000000u)
                             : __uint_as_float(~u);
}

__global__ void init_kernel(const float* __restrict__ emb_avg,
                            const float* __restrict__ cs,
                            float* __restrict__ out, char* __restrict__ ws) {
    int i = blockIdx.x * blockDim.x + threadIdx.x;   // grid covers K*D/4
    const float4* e4 = (const float4*)emb_avg;
    float4* o4 = (float4*)(out + EMB_OFF);
    if (i < K * D / 4) {
        float4 v = e4[i];
        v.x *= DECAY; v.y *= DECAY; v.z *= DECAY; v.w *= DECAY;
        o4[i] = v;
    }
    if (i < K) out[CS_OFF + i] = cs[i] * DECAY;
    if (i < N) ((unsigned long long*)(ws + WS_RES))[i] = ~0ull;
    if (i == 0) {
        ((unsigned*)(ws + WS_CNT))[0] = 0u;
        ((float*)(ws + WS_CNT))[1] = 0.f;
    }
}

__global__ void c2_kernel(const float* __restrict__ cb, float* __restrict__ c2) {
    int k = blockIdx.x;
    int lane = threadIdx.x;
    const float4* row = (const float4*)(cb + (long)k * D);
    float4 v = row[lane];
    float s = v.x * v.x + v.y * v.y + v.z * v.z + v.w * v.w;
    for (int off = 32; off; off >>= 1) s += __shfl_xor(s, off);
    if (lane == 0) c2[k] = s;
}

// ---------------- fp16 MFMA distance GEMM with top-2 tracking ----------------
__global__ __launch_bounds__(GT, 2) void gemm_kernel(
        const float* __restrict__ z, const float* __restrict__ cb,
        const float* __restrict__ c2, ulonglong2* __restrict__ tops) {
    __shared__ _Float16 As[BMt * 256];          // 128 KB, swizzled
    __shared__ _Float16 Bs[2][BNt * 32];        // 2 x 8 KB, swizzled
    __shared__ float c2s[BNt];
    __shared__ unsigned long long L1[BMt];      // block-level top1 (score|idx)
    __shared__ unsigned L2s[BMt];               // block-level top2 score

    const int tid = threadIdx.x;
    const int lane = tid & 63;
    const int wave = tid >> 6;                  // 8 waves: 4(M) x 2(N)
    const int wm = wave >> 1, wn = wave & 1;
    const long rowBase = (long)blockIdx.x * BMt;
    const int kbase = blockIdx.y * (K / KSPLIT);

    // ---- stage A (z rows) once: fp32 -> fp16, swizzled ----
    for (int i = 0; i < 16; ++i) {
        int id = tid + i * GT;                  // 8192 chunks of 8 floats
        int r = id >> 5, dseg = (id & 31) * 8;
        const float4* src = (const float4*)(z + (rowBase + r) * D + dseg);
        float4 v0 = src[0], v1 = src[1];
        union { _Float16 h[8]; ulonglong2 u; } t;
        t.h[0] = (_Float16)v0.x; t.h[1] = (_Float16)v0.y;
        t.h[2] = (_Float16)v0.z; t.h[3] = (_Float16)v0.w;
        t.h[4] = (_Float16)v1.x; t.h[5] = (_Float16)v1.y;
        t.h[6] = (_Float16)v1.z; t.h[7] = (_Float16)v1.w;
        int byte = (r * 256 + dseg) * 2;
        byte ^= (r & 7) << 4;
        *(ulonglong2*)((char*)As + byte) = t.u;
    }
    // stage B chunk 0
    {
        int c = tid >> 2, dseg = (tid & 3) * 8;
        const float* s = cb + (long)(kbase + c) * D + dseg;
        float4 b0 = *(const float4*)s, b1 = *((const float4*)s + 1);
        union { _Float16 h[8]; ulonglong2 u; } t;
        t.h[0] = (_Float16)b0.x; t.h[1] = (_Float16)b0.y;
        t.h[2] = (_Float16)b0.z; t.h[3] = (_Float16)b0.w;
        t.h[4] = (_Float16)b1.x; t.h[5] = (_Float16)b1.y;
        t.h[6] = (_Float16)b1.z; t.h[7] = (_Float16)b1.w;
        int byte = (c * 32 + dseg) * 2;
        byte ^= (c & 7) << 4;
        *(ulonglong2*)((char*)&Bs[0][0] + byte) = t.u;
    }
    if (tid < BNt) c2s[tid] = c2[kbase + tid];
    if (tid < BMt) { L1[tid] = ~0ull; L2s[tid] = 0xFFFFFFFFu; }
    __syncthreads();

    // per-thread A/B frag byte offsets. A: xor applied AFTER adding dc.
    int aBase[4], aSwz[4], bOff[4];
#pragma unroll
    for (int fr = 0; fr < 4; ++fr) {
        int r = wm * 64 + fr * 16 + (lane & 15);
        aBase[fr] = r * 512 + (lane >> 4) * 16;
        aSwz[fr] = (r & 7) << 4;
    }
#pragma unroll
    for (int fc = 0; fc < 4; ++fc) {
        int c = wn * 64 + fc * 16 + (lane & 15);
        int byte = c * 64 + (lane >> 4) * 16;
        bOff[fc] = byte ^ ((c & 7) << 4);
    }

    f32x4 acc[4][4];
    unsigned long long t1[16];
    unsigned t2[16];
#pragma unroll
    for (int s = 0; s < 16; ++s) { t1[s] = ~0ull; t2[s] = 0xFFFFFFFFu; }
    float c2v[4];

    const int NCH = (K / KSPLIT / BNt) * 8;      // 256 chunks
    for (int j = 0; j < NCH; ++j) {
        const int kb = j >> 3, dcI = j & 7, dc = dcI * 32;
        const int cur = j & 1;
        // prefetch next chunk (global -> regs)
        float4 p0, p1;
        const bool pf = (j + 1 < NCH);
        if (pf) {
            int jj = j + 1;
            int c = tid >> 2, dseg = (tid & 3) * 8;
            const float* s = cb + (long)(kbase + (jj >> 3) * BNt + c) * D
                             + (jj & 7) * 32 + dseg;
            p0 = *(const float4*)s; p1 = *((const float4*)s + 1);
        }
        // compute current chunk
        if (dcI == 0) {
#pragma unroll
            for (int a = 0; a < 4; ++a)
#pragma unroll
                for (int b = 0; b < 4; ++b) acc[a][b] = (f32x4)0.f;
#pragma unroll
            for (int fc = 0; fc < 4; ++fc)
                c2v[fc] = c2s[wn * 64 + fc * 16 + (lane & 15)];
        }
        f16x8 aF[4], bF[4];
#pragma unroll
        for (int fr = 0; fr < 4; ++fr)
            aF[fr] = *(const f16x8*)((const char*)As +
                        ((aBase[fr] + dc * 2) ^ aSwz[fr]));
#pragma unroll
        for (int fc = 0; fc < 4; ++fc)
            bF[fc] = *(const f16x8*)((const char*)&Bs[cur][0] + bOff[fc]);
#pragma unroll
        for (int fr = 0; fr < 4; ++fr)
#pragma unroll
            for (int fc = 0; fc < 4; ++fc)
                acc[fr][fc] = __builtin_amdgcn_mfma_f32_16x16x32_f16(
                    aF[fr], bF[fc], acc[fr][fc], 0, 0, 0);
        if (dcI == 7) {
            // score + top2 update
#pragma unroll
            for (int fc = 0; fc < 4; ++fc) {
                int gcol = kbase + kb * BNt + wn * 64 + fc * 16 + (lane & 15);
#pragma unroll
                for (int fr = 0; fr < 4; ++fr)
#pragma unroll
                    for (int r = 0; r < 4; ++r) {
                        float s = fmaf(-2.f, acc[fr][fc][r], c2v[fc]);
                        unsigned su = transScore(s);
                        unsigned long long u =
                            ((unsigned long long)su << 32) | (unsigned)gcol;
                        int slot = fr * 4 + r;
                        unsigned old1 = (unsigned)(t1[slot] >> 32);
                        t1[slot] = u < t1[slot] ? u : t1[slot];
                        unsigned mx = su > old1 ? su : old1;
                        t2[slot] = t2[slot] < mx ? t2[slot] : mx;
                    }
            }
        }
        __syncthreads();             // everyone done reading Bs[cur]/c2s
        if (pf) {
            int jj = j + 1;
            int c = tid >> 2, dseg = (tid & 3) * 8;
            union { _Float16 h[8]; ulonglong2 u; } t;
            t.h[0] = (_Float16)p0.x; t.h[1] = (_Float16)p0.y;
            t.h[2] = (_Float16)p0.z; t.h[3] = (_Float16)p0.w;
            t.h[4] = (_Float16)p1.x; t.h[5] = (_Float16)p1.y;
            t.h[6] = (_Float16)p1.z; t.h[7] = (_Float16)p1.w;
            int byte = (c * 32 + dseg) * 2;
            byte ^= (c & 7) << 4;
            *(ulonglong2*)((char*)&Bs[cur ^ 1][0] + byte) = t.u;
            if ((jj & 7) == 0 && tid < BNt)     // new kb: stage its c2
                c2s[tid] = c2[kbase + (jj >> 3) * BNt + tid];
        }
        __syncthreads();
    }

    // intra-wave top2 merge over the 16 lanes sharing each row
#pragma unroll
    for (int m = 1; m < 16; m <<= 1) {
#pragma unroll
        for (int s = 0; s < 16; ++s) {
            unsigned long long o1 = __shfl_xor(t1[s], m);
            unsigned o2 = (unsigned)__shfl_xor((int)t2[s], m);
            unsigned a1 = (unsigned)(t1[s] >> 32), b1 = (unsigned)(o1 >> 32);
            unsigned mx = a1 > b1 ? a1 : b1;
            unsigned nt2 = t2[s] < o2 ? t2[s] : o2;
            nt2 = nt2 < mx ? nt2 : mx;
            t1[s] = o1 < t1[s] ? o1 : t1[s];
            t2[s] = nt2;
        }
    }
    // cross-wave (wn=0/1) top2 merge via LDS atomicMin-displacement
    if ((lane & 15) == 0) {
#pragma unroll
        for (int s = 0; s < 16; ++s) {
            int row = wm * 64 + (s >> 2) * 16 + (lane >> 4) * 4 + (s & 3);
            unsigned long long old1 = atomicMin(&L1[row], t1[s]);
            unsigned long long cand = t1[s] < old1 ? old1 : t1[s];
            atomicMin(&L2s[row], (unsigned)(cand >> 32));
            atomicMin(&L2s[row], t2[s]);
        }
    }
    __syncthreads();
    if (tid < BMt) {
        ulonglong2 v; v.x = L1[tid]; v.y = (unsigned long long)L2s[tid];
        tops[(rowBase + tid) * KSPLIT + blockIdx.y] = v;
    }
}

__global__ void merge_kernel(const ulonglong2* __restrict__ tops,
                             float* __restrict__ out, int* __restrict__ idxArr,
                             unsigned* __restrict__ flagCount,
                             int* __restrict__ flagRows) {
    int row = blockIdx.x * 256 + threadIdx.x;
    ulonglong2 a = tops[row * 2], b = tops[row * 2 + 1];
    unsigned long long t1 = a.x < b.x ? a.x : b.x;
    unsigned a1 = (unsigned)(a.x >> 32), b1 = (unsigned)(b.x >> 32);
    unsigned mx = a1 > b1 ? a1 : b1;
    unsigned t2 = (unsigned)a.y < (unsigned)b.y ? (unsigned)a.y : (unsigned)b.y;
    t2 = t2 < mx ? t2 : mx;
    float s1 = untransScore((unsigned)(t1 >> 32));
    float s2 = untransScore(t2);
    int idx = (int)(t1 & 0xFFFFFFFFull);
    idxArr[row] = idx;
    out[IDX_OFF + row] = (float)idx;
    if (s2 - s1 <= DELTA) {
        unsigned p = atomicAdd(flagCount, 1u);
        flagRows[p] = row;
    }
}

// exact fp32 rescore of flagged rows. Grid = RGW group-slots x RKS K-splits.
// 64 rows staged in LDS per group; 4 accumulators for FMA-latency ILP.
__global__ __launch_bounds__(512) void resolve_kernel(
        const float* __restrict__ z, const float* __restrict__ cb,
        const float* __restrict__ c2, const unsigned* __restrict__ flagCount,
        const int* __restrict__ flagRows, unsigned long long* __restrict__ resolved) {
    __shared__ float zs[RGRP][260];
    const int cnt = (int)*flagCount;
    const int tid = threadIdx.x;
    const int ks = blockIdx.x & (RKS - 1);
    const int k0 = ks * (K / RKS);                  // 1024 codes per split
    for (int g = blockIdx.x >> 3; g * RGRP < cnt; g += RGW) {
        __syncthreads();
        // stage 64 flagged rows' z (4096 float4 slots / 512 threads)
#pragma unroll
        for (int i = 0; i < 8; ++i) {
            int id = tid + i * 512;
            int r = id >> 6, j = id & 63;
            int fi = g * RGRP + r;
            int row = flagRows[fi < cnt ? fi : g * RGRP];
            *(float4*)&zs[r][j * 4] = *(const float4*)(z + (long)row * D + j * 4);
        }
        __syncthreads();
        int r = tid >> 3, cl = tid & 7;
        int fi = g * RGRP + r;
        unsigned long long best = ~0ull;
        for (int kk = 0; kk < K / RKS / 8; ++kk) {  // 128
            int k = k0 + kk * 8 + cl;
            const float4* crow = (const float4*)(cb + (long)k * D);
            float d0 = 0.f, d1 = 0.f, d2 = 0.f, d3 = 0.f;
#pragma unroll
            for (int j = 0; j < 64; j += 4) {
                float4 ca = crow[j],     cbv = crow[j + 1];
                float4 cc = crow[j + 2], cd  = crow[j + 3];
                float4 za = *(const float4*)&zs[r][j * 4];
                float4 zb = *(const float4*)&zs[r][j * 4 + 4];
                float4 zc = *(const float4*)&zs[r][j * 4 + 8];
                float4 zd = *(const float4*)&zs[r][j * 4 + 12];
                d0 = fmaf(za.x, ca.x, d0); d0 = fmaf(za.y, ca.y, d0);
                d0 = fmaf(za.z, ca.z, d0); d0 = fmaf(za.w, ca.w, d0);
                d1 = fmaf(zb.x, cbv.x, d1); d1 = fmaf(zb.y, cbv.y, d1);
                d1 = fmaf(zb.z, cbv.z, d1); d1 = fmaf(zb.w, cbv.w, d1);
                d2 = fmaf(zc.x, cc.x, d2); d2 = fmaf(zc.y, cc.y, d2);
                d2 = fmaf(zc.z, cc.z, d2); d2 = fmaf(zc.w, cc.w, d2);
                d3 = fmaf(zd.x, cd.x, d3); d3 = fmaf(zd.y, cd.y, d3);
                d3 = fmaf(zd.z, cd.z, d3); d3 = fmaf(zd.w, cd.w, d3);
            }
            float dot = (d0 + d1) + (d2 + d3);
            float s = fmaf(-2.f, dot, c2[k]);
            unsigned long long u =
                ((unsigned long long)transScore(s) << 32) | (unsigned)k;
            best = u < best ? u : best;
        }
        // merge the 8 code-lanes (cl) of this row
#pragma unroll
        for (int m = 1; m < 8; m <<= 1) {
            unsigned long long o = __shfl_xor(best, m);
            best = o < best ? o : best;
        }
        if (cl == 0 && fi < cnt)
            atomicMin(&resolved[flagRows[fi]], best);
    }
}

__global__ void writeback_kernel(const unsigned* __restrict__ flagCount,
                                 const int* __restrict__ flagRows,
                                 const unsigned long long* __restrict__ resolved,
                                 int* __restrict__ idxArr, float* __restrict__ out) {
    int i = blockIdx.x * 256 + threadIdx.x;
    if (i < (int)*flagCount) {
        int row = flagRows[i];
        int idx = (int)(resolved[row] & 0xFFFFFFFFull);
        idxArr[row] = idx;
        out[IDX_OFF + row] = (float)idx;
    }
}

__global__ __launch_bounds__(512) void epilogue_kernel(
        const float* __restrict__ z, const float* __restrict__ cb,
        const int* __restrict__ idxArr, float* __restrict__ out) {
    int tid = threadIdx.x;
    int r = tid >> 2, seg = tid & 3;
    int gRow = blockIdx.x * 128 + r;
    int code = idxArr[gRow];
    if (seg == 0) atomicAdd(&out[CS_OFF + code], OMD);
    const float4* cbv = (const float4*)(cb + (long)code * D + seg * 64);
    const float4* zv  = (const float4*)(z + (long)gRow * D + seg * 64);
    float4* qv = (float4*)(out + Q_OFF + (long)gRow * D + seg * 64);
    float*  er = out + EMB_OFF + (long)code * D + seg * 64;
#pragma unroll 4
    for (int i = 0; i < 16; ++i) {
        float4 cv = cbv[i];
        qv[i] = cv;
        float4 zt = zv[i];
        atomicAdd(&er[i * 4 + 0], OMD * zt.x);
        atomicAdd(&er[i * 4 + 1], OMD * zt.y);
        atomicAdd(&er[i * 4 + 2], OMD * zt.z);
        atomicAdd(&er[i * 4 + 3], OMD * zt.w);
    }
}

__global__ void reduce_n(const float* __restrict__ out_cs, float* __restrict__ nacc) {
    int i = blockIdx.x * 256 + threadIdx.x;
    float v = out_cs[i];
    for (int off = 32; off; off >>= 1) v += __shfl_xor(v, off);
    __shared__ float wsum[4];
    int lane = threadIdx.x & 63, w = threadIdx.x >> 6;
    if (lane == 0) wsum[w] = v;
    __syncthreads();
    if (threadIdx.x == 0) atomicAdd(nacc, wsum[0] + wsum[1] + wsum[2] + wsum[3]);
}

__global__ void finalize_kernel(const float* __restrict__ nacc, float* __restrict__ out) {
    int k = blockIdx.x, d = threadIdx.x;
    float n = *nacc;
    float ncs = out[CS_OFF + k];
    float smoothed = (ncs + EPS) / (n + (float)K * EPS) * n;
    out[CB_OFF + (long)k * D + d] = out[EMB_OFF + (long)k * D + d] / smoothed;
}

extern "C" void kernel_launch(void* const* d_in, const int* in_sizes, int n_in,
                              void* d_out, int out_size, void* d_ws, size_t ws_size,
                              hipStream_t stream) {
    const float* z   = (const float*)d_in[0];
    const float* cb  = (const float*)d_in[1];
    const float* emb = (const float*)d_in[2];
    const float* cs  = (const float*)d_in[3];
    float* out = (float*)d_out;
    char* ws = (char*)d_ws;

    ulonglong2* tops = (ulonglong2*)(ws + WS_TOPS);
    unsigned long long* resolved = (unsigned long long*)(ws + WS_RES);
    int* idxArr = (int*)(ws + WS_IDX);
    float* c2 = (float*)(ws + WS_C2);
    int* flagRows = (int*)(ws + WS_FLAG);
    unsigned* flagCount = (unsigned*)(ws + WS_CNT);
    float* nacc = (float*)(ws + WS_CNT) + 1;

    init_kernel<<<(K * D / 4 + 255) / 256, 256, 0, stream>>>(emb, cs, out, ws);
    c2_kernel<<<K, 64, 0, stream>>>(cb, c2);
    dim3 ggrid(N / BMt, KSPLIT);
    gemm_kernel<<<ggrid, GT, 0, stream>>>(z, cb, c2, tops);
    merge_kernel<<<N / 256, 256, 0, stream>>>(tops, out, idxArr, flagCount, flagRows);
    resolve_kernel<<<RGW * RKS, 512, 0, stream>>>(z, cb, c2, flagCount, flagRows, resolved);
    writeback_kernel<<<N / 256, 256, 0, stream>>>(flagCount, flagRows, resolved, idxArr, out);
    epilogue_kernel<<<N / 128, 512, 0, stream>>>(z, cb, idxArr, out);
    reduce_n<<<K / 256, 256, 0, stream>>>(out + CS_OFF, nacc);
    finalize_kernel<<<K, 256, 0, stream>>>(nacc, out);
}

// Round 6
// 1063.883 us; speedup vs baseline: 2.9345x; 2.9345x over previous
//
#include <hip/hip_runtime.h>

// EMA codebook update (VQ-VAE), MI355X. fp16-MFMA distance filter + exact
// fp32 rescore for near-ties. N=32768, K=8192, D=256.
// R6: resolve rebuilt as R2-style tiled fp32 mini-argmin over gathered rows
//     (coalesced LDS staging, 8x4 reg tile, K-split x group-slot grid).

#define DECAY 0.99f
#define OMD 0.01f
#define EPS 1e-5f
#define DELTA 0.3f

constexpr int N = 32768, K = 8192, D = 256;
constexpr int KSPLIT = 2;               // gemm grid: 128 row-tiles x 2 code-splits
constexpr int BMt = 256, BNt = 128;     // gemm tile
constexpr int GT = 512;                 // gemm threads (8 waves)

// resolve config (R2-style tile)
constexpr int RBM = 128;                // flagged rows per group
constexpr int RBN = 128;                // code tile per kb step
constexpr int RKS = 32;                 // K splits (256 codes each)
constexpr int RSL = 32;                 // group slots
constexpr int RDC = 32;                 // d-chunk

typedef _Float16 f16x8 __attribute__((ext_vector_type(8)));
typedef float f32x4 __attribute__((ext_vector_type(4)));

// d_out layout (floats, reference return order)
constexpr long Q_OFF   = 0;
constexpr long IDX_OFF = (long)N * D;
constexpr long CB_OFF  = IDX_OFF + N;
constexpr long EMB_OFF = CB_OFF + (long)K * D;
constexpr long CS_OFF  = EMB_OFF + (long)K * D;

// ws layout (bytes)
constexpr long WS_TOPS = 0;                          // ulonglong2[N*KSPLIT]
constexpr long WS_RES  = WS_TOPS + (long)N * 2 * 16; // u64[N] resolved
constexpr long WS_IDX  = WS_RES + (long)N * 8;       // int[N]
constexpr long WS_C2   = WS_IDX + (long)N * 4;       // float[K]
constexpr long WS_FLAG = WS_C2 + (long)K * 4;        // int[N] flagged rows
constexpr long WS_CNT  = WS_FLAG + (long)N * 4;      // [0] u32 count, [1] f32 nacc

__device__ inline unsigned transScore(float s) {
    unsigned u = __float_as_uint(s);
    return u ^ ((unsigned)((int)u >> 31) | 0x80000000u);   // order-preserving
}
__device__ inline float untransScore(unsigned u) {
    return (u & 0x80000000u) ? __uint_as_float(u ^ 0x80000000u)
                             : __uint_as_float(~u);
}

__global__ void init_kernel(const float* __restrict__ emb_avg,
                            const float* __restrict__ cs,
                            float* __restrict__ out, char* __restrict__ ws) {
    int i = blockIdx.x * blockDim.x + threadIdx.x;   // grid covers K*D/4
    const float4* e4 = (const float4*)emb_avg;
    float4* o4 = (float4*)(out + EMB_OFF);
    if (i < K * D / 4) {
        float4 v = e4[i];
        v.x *= DECAY; v.y *= DECAY; v.z *= DECAY; v.w *= DECAY;
        o4[i] = v;
    }
    if (i < K) out[CS_OFF + i] = cs[i] * DECAY;
    if (i < N) ((unsigned long long*)(ws + WS_RES))[i] = ~0ull;
    if (i == 0) {
        ((unsigned*)(ws + WS_CNT))[0] = 0u;
        ((float*)(ws + WS_CNT))[1] = 0.f;
    }
}

__global__ void c2_kernel(const float* __restrict__ cb, float* __restrict__ c2) {
    int k = blockIdx.x;
    int lane = threadIdx.x;
    const float4* row = (const float4*)(cb + (long)k * D);
    float4 v = row[lane];
    float s = v.x * v.x + v.y * v.y + v.z * v.z + v.w * v.w;
    for (int off = 32; off; off >>= 1) s += __shfl_xor(s, off);
    if (lane == 0) c2[k] = s;
}

// ---------------- fp16 MFMA distance GEMM with top-2 tracking ----------------
__global__ __launch_bounds__(GT, 2) void gemm_kernel(
        const float* __restrict__ z, const float* __restrict__ cb,
        const float* __restrict__ c2, ulonglong2* __restrict__ tops) {
    __shared__ _Float16 As[BMt * 256];          // 128 KB, swizzled
    __shared__ _Float16 Bs[2][BNt * 32];        // 2 x 8 KB, swizzled
    __shared__ float c2s[BNt];
    __shared__ unsigned long long L1[BMt];      // block-level top1 (score|idx)
    __shared__ unsigned L2s[BMt];               // block-level top2 score

    const int tid = threadIdx.x;
    const int lane = tid & 63;
    const int wave = tid >> 6;                  // 8 waves: 4(M) x 2(N)
    const int wm = wave >> 1, wn = wave & 1;
    const long rowBase = (long)blockIdx.x * BMt;
    const int kbase = blockIdx.y * (K / KSPLIT);

    // ---- stage A (z rows) once: fp32 -> fp16, swizzled ----
    for (int i = 0; i < 16; ++i) {
        int id = tid + i * GT;                  // 8192 chunks of 8 floats
        int r = id >> 5, dseg = (id & 31) * 8;
        const float4* src = (const float4*)(z + (rowBase + r) * D + dseg);
        float4 v0 = src[0], v1 = src[1];
        union { _Float16 h[8]; ulonglong2 u; } t;
        t.h[0] = (_Float16)v0.x; t.h[1] = (_Float16)v0.y;
        t.h[2] = (_Float16)v0.z; t.h[3] = (_Float16)v0.w;
        t.h[4] = (_Float16)v1.x; t.h[5] = (_Float16)v1.y;
        t.h[6] = (_Float16)v1.z; t.h[7] = (_Float16)v1.w;
        int byte = (r * 256 + dseg) * 2;
        byte ^= (r & 7) << 4;
        *(ulonglong2*)((char*)As + byte) = t.u;
    }
    // stage B chunk 0
    {
        int c = tid >> 2, dseg = (tid & 3) * 8;
        const float* s = cb + (long)(kbase + c) * D + dseg;
        float4 b0 = *(const float4*)s, b1 = *((const float4*)s + 1);
        union { _Float16 h[8]; ulonglong2 u; } t;
        t.h[0] = (_Float16)b0.x; t.h[1] = (_Float16)b0.y;
        t.h[2] = (_Float16)b0.z; t.h[3] = (_Float16)b0.w;
        t.h[4] = (_Float16)b1.x; t.h[5] = (_Float16)b1.y;
        t.h[6] = (_Float16)b1.z; t.h[7] = (_Float16)b1.w;
        int byte = (c * 32 + dseg) * 2;
        byte ^= (c & 7) << 4;
        *(ulonglong2*)((char*)&Bs[0][0] + byte) = t.u;
    }
    if (tid < BNt) c2s[tid] = c2[kbase + tid];
    if (tid < BMt) { L1[tid] = ~0ull; L2s[tid] = 0xFFFFFFFFu; }
    __syncthreads();

    // per-thread A/B frag byte offsets. A: xor applied AFTER adding dc.
    int aBase[4], aSwz[4], bOff[4];
#pragma unroll
    for (int fr = 0; fr < 4; ++fr) {
        int r = wm * 64 + fr * 16 + (lane & 15);
        aBase[fr] = r * 512 + (lane >> 4) * 16;
        aSwz[fr] = (r & 7) << 4;
    }
#pragma unroll
    for (int fc = 0; fc < 4; ++fc) {
        int c = wn * 64 + fc * 16 + (lane & 15);
        int byte = c * 64 + (lane >> 4) * 16;
        bOff[fc] = byte ^ ((c & 7) << 4);
    }

    f32x4 acc[4][4];
    unsigned long long t1[16];
    unsigned t2[16];
#pragma unroll
    for (int s = 0; s < 16; ++s) { t1[s] = ~0ull; t2[s] = 0xFFFFFFFFu; }
    float c2v[4];

    const int NCH = (K / KSPLIT / BNt) * 8;      // 256 chunks
    for (int j = 0; j < NCH; ++j) {
        const int kb = j >> 3, dcI = j & 7, dc = dcI * 32;
        const int cur = j & 1;
        // prefetch next chunk (global -> regs)
        float4 p0, p1;
        const bool pf = (j + 1 < NCH);
        if (pf) {
            int jj = j + 1;
            int c = tid >> 2, dseg = (tid & 3) * 8;
            const float* s = cb + (long)(kbase + (jj >> 3) * BNt + c) * D
                             + (jj & 7) * 32 + dseg;
            p0 = *(const float4*)s; p1 = *((const float4*)s + 1);
        }
        // compute current chunk
        if (dcI == 0) {
#pragma unroll
            for (int a = 0; a < 4; ++a)
#pragma unroll
                for (int b = 0; b < 4; ++b) acc[a][b] = (f32x4)0.f;
#pragma unroll
            for (int fc = 0; fc < 4; ++fc)
                c2v[fc] = c2s[wn * 64 + fc * 16 + (lane & 15)];
        }
        f16x8 aF[4], bF[4];
#pragma unroll
        for (int fr = 0; fr < 4; ++fr)
            aF[fr] = *(const f16x8*)((const char*)As +
                        ((aBase[fr] + dc * 2) ^ aSwz[fr]));
#pragma unroll
        for (int fc = 0; fc < 4; ++fc)
            bF[fc] = *(const f16x8*)((const char*)&Bs[cur][0] + bOff[fc]);
#pragma unroll
        for (int fr = 0; fr < 4; ++fr)
#pragma unroll
            for (int fc = 0; fc < 4; ++fc)
                acc[fr][fc] = __builtin_amdgcn_mfma_f32_16x16x32_f16(
                    aF[fr], bF[fc], acc[fr][fc], 0, 0, 0);
        if (dcI == 7) {
            // score + top2 update
#pragma unroll
            for (int fc = 0; fc < 4; ++fc) {
                int gcol = kbase + kb * BNt + wn * 64 + fc * 16 + (lane & 15);
#pragma unroll
                for (int fr = 0; fr < 4; ++fr)
#pragma unroll
                    for (int r = 0; r < 4; ++r) {
                        float s = fmaf(-2.f, acc[fr][fc][r], c2v[fc]);
                        unsigned su = transScore(s);
                        unsigned long long u =
                            ((unsigned long long)su << 32) | (unsigned)gcol;
                        int slot = fr * 4 + r;
                        unsigned old1 = (unsigned)(t1[slot] >> 32);
                        t1[slot] = u < t1[slot] ? u : t1[slot];
                        unsigned mx = su > old1 ? su : old1;
                        t2[slot] = t2[slot] < mx ? t2[slot] : mx;
                    }
            }
        }
        __syncthreads();             // everyone done reading Bs[cur]/c2s
        if (pf) {
            int jj = j + 1;
            int c = tid >> 2, dseg = (tid & 3) * 8;
            union { _Float16 h[8]; ulonglong2 u; } t;
            t.h[0] = (_Float16)p0.x; t.h[1] = (_Float16)p0.y;
            t.h[2] = (_Float16)p0.z; t.h[3] = (_Float16)p0.w;
            t.h[4] = (_Float16)p1.x; t.h[5] = (_Float16)p1.y;
            t.h[6] = (_Float16)p1.z; t.h[7] = (_Float16)p1.w;
            int byte = (c * 32 + dseg) * 2;
            byte ^= (c & 7) << 4;
            *(ulonglong2*)((char*)&Bs[cur ^ 1][0] + byte) = t.u;
            if ((jj & 7) == 0 && tid < BNt)     // new kb: stage its c2
                c2s[tid] = c2[kbase + (jj >> 3) * BNt + tid];
        }
        __syncthreads();
    }

    // intra-wave top2 merge over the 16 lanes sharing each row
#pragma unroll
    for (int m = 1; m < 16; m <<= 1) {
#pragma unroll
        for (int s = 0; s < 16; ++s) {
            unsigned long long o1 = __shfl_xor(t1[s], m);
            unsigned o2 = (unsigned)__shfl_xor((int)t2[s], m);
            unsigned a1 = (unsigned)(t1[s] >> 32), b1 = (unsigned)(o1 >> 32);
            unsigned mx = a1 > b1 ? a1 : b1;
            unsigned nt2 = t2[s] < o2 ? t2[s] : o2;
            nt2 = nt2 < mx ? nt2 : mx;
            t1[s] = o1 < t1[s] ? o1 : t1[s];
            t2[s] = nt2;
        }
    }
    // cross-wave (wn=0/1) top2 merge via LDS atomicMin-displacement
    if ((lane & 15) == 0) {
#pragma unroll
        for (int s = 0; s < 16; ++s) {
            int row = wm * 64 + (s >> 2) * 16 + (lane >> 4) * 4 + (s & 3);
            unsigned long long old1 = atomicMin(&L1[row], t1[s]);
            unsigned long long cand = t1[s] < old1 ? old1 : t1[s];
            atomicMin(&L2s[row], (unsigned)(cand >> 32));
            atomicMin(&L2s[row], t2[s]);
        }
    }
    __syncthreads();
    if (tid < BMt) {
        ulonglong2 v; v.x = L1[tid]; v.y = (unsigned long long)L2s[tid];
        tops[(rowBase + tid) * KSPLIT + blockIdx.y] = v;
    }
}

__global__ void merge_kernel(const ulonglong2* __restrict__ tops,
                             float* __restrict__ out, int* __restrict__ idxArr,
                             unsigned* __restrict__ flagCount,
                             int* __restrict__ flagRows) {
    int row = blockIdx.x * 256 + threadIdx.x;
    ulonglong2 a = tops[row * 2], b = tops[row * 2 + 1];
    unsigned long long t1 = a.x < b.x ? a.x : b.x;
    unsigned a1 = (unsigned)(a.x >> 32), b1 = (unsigned)(b.x >> 32);
    unsigned mx = a1 > b1 ? a1 : b1;
    unsigned t2 = (unsigned)a.y < (unsigned)b.y ? (unsigned)a.y : (unsigned)b.y;
    t2 = t2 < mx ? t2 : mx;
    float s1 = untransScore((unsigned)(t1 >> 32));
    float s2 = untransScore(t2);
    int idx = (int)(t1 & 0xFFFFFFFFull);
    idxArr[row] = idx;
    out[IDX_OFF + row] = (float)idx;
    if (s2 - s1 <= DELTA) {
        unsigned p = atomicAdd(flagCount, 1u);
        flagRows[p] = row;
    }
}

// exact fp32 rescore of flagged rows. Grid = (RSL group slots, RKS K-splits).
// R2-style tile: 128 gathered rows x 256 codes, LDS-transposed staging,
// 8x4 register tile, shfl argmin, u64 atomicMin merge into resolved[].
__global__ __launch_bounds__(512) void resolve_kernel(
        const float* __restrict__ z, const float* __restrict__ cb,
        const float* __restrict__ c2, const unsigned* __restrict__ flagCount,
        const int* __restrict__ flagRows, unsigned long long* __restrict__ resolved) {
    __shared__ float zT[RDC][RBM + 4];
    __shared__ float cT[RDC][RBN + 4];
    __shared__ float c2s[RBN];
    __shared__ int rid[RBM];

    const int cnt = (int)*flagCount;
    const int tid = threadIdx.x;
    const int tx = tid & 31, ty = tid >> 5;
    const int rbase = ty * 8, cbase = tx * 4;
    const int k0 = blockIdx.y * (K / RKS);          // 256 codes per split

    for (int g = blockIdx.x; g * RBM < cnt; g += RSL) {
        __syncthreads();                // previous iteration fully done
        if (tid < RBM) {
            int fi = g * RBM + tid;
            rid[tid] = flagRows[fi < cnt ? fi : cnt - 1];   // pad = dup row (harmless)
        }

        float bestV[8]; int bestI[8];
#pragma unroll
        for (int r = 0; r < 8; ++r) { bestV[r] = 3.4e38f; bestI[r] = 0; }

        for (int kb = k0; kb < k0 + K / RKS; kb += RBN) {   // 2 iterations
            __syncthreads();            // prior score-phase reads of c2s done
            if (tid < RBN) c2s[tid] = c2[kb + tid];

            float acc[8][4];
#pragma unroll
            for (int r = 0; r < 8; ++r)
#pragma unroll
                for (int c = 0; c < 4; ++c) acc[r][c] = 0.f;

            for (int dc = 0; dc < D; dc += RDC) {
                __syncthreads();        // prior compute reads of zT/cT done
#pragma unroll
                for (int s = 0; s < 2; ++s) {
                    int f = tid + s * 512;          // 1024 float4 slots
                    int row = f >> 3, dq = f & 7;
                    float4 v = *(const float4*)(z + (long)rid[row] * D + dc + dq * 4);
                    zT[dq * 4 + 0][row] = v.x; zT[dq * 4 + 1][row] = v.y;
                    zT[dq * 4 + 2][row] = v.z; zT[dq * 4 + 3][row] = v.w;
                    float4 w = *(const float4*)(cb + (long)(kb + row) * D + dc + dq * 4);
                    cT[dq * 4 + 0][row] = w.x; cT[dq * 4 + 1][row] = w.y;
                    cT[dq * 4 + 2][row] = w.z; cT[dq * 4 + 3][row] = w.w;
                }
                __syncthreads();
#pragma unroll
                for (int d = 0; d < RDC; ++d) {
                    float a[8], b[4];
                    *(float4*)&a[0] = *(const float4*)&zT[d][rbase];
                    *(float4*)&a[4] = *(const float4*)&zT[d][rbase + 4];
                    *(float4*)&b[0] = *(const float4*)&cT[d][cbase];
#pragma unroll
                    for (int r = 0; r < 8; ++r)
#pragma unroll
                        for (int c = 0; c < 4; ++c)
                            acc[r][c] = fmaf(a[r], b[c], acc[r][c]);
                }
            }
            // score phase: c2 - 2*zc (z2 row-constant, argmin-invariant)
#pragma unroll
            for (int c = 0; c < 4; ++c) {
                float cc = c2s[cbase + c];
                int col = kb + cbase + c;
#pragma unroll
                for (int r = 0; r < 8; ++r) {
                    float score = fmaf(-2.f, acc[r][c], cc);
                    if (score < bestV[r]) { bestV[r] = score; bestI[r] = col; }
                }
            }
        }
        // reduce across the 32 tx-lanes sharing rows; first-index ties
#pragma unroll
        for (int off = 16; off; off >>= 1) {
#pragma unroll
            for (int r = 0; r < 8; ++r) {
                float ov = __shfl_xor(bestV[r], off);
                int   oi = __shfl_xor(bestI[r], off);
                if (ov < bestV[r] || (ov == bestV[r] && oi < bestI[r])) {
                    bestV[r] = ov; bestI[r] = oi;
                }
            }
        }
        if (tx == 0) {
#pragma unroll
            for (int r = 0; r < 8; ++r) {
                unsigned long long u =
                    ((unsigned long long)transScore(bestV[r]) << 32)
                    | (unsigned)bestI[r];
                atomicMin(&resolved[rid[rbase + r]], u);
            }
        }
    }
}

__global__ void writeback_kernel(const unsigned* __restrict__ flagCount,
                                 const int* __restrict__ flagRows,
                                 const unsigned long long* __restrict__ resolved,
                                 int* __restrict__ idxArr, float* __restrict__ out) {
    int i = blockIdx.x * 256 + threadIdx.x;
    if (i < (int)*flagCount) {
        int row = flagRows[i];
        int idx = (int)(resolved[row] & 0xFFFFFFFFull);
        idxArr[row] = idx;
        out[IDX_OFF + row] = (float)idx;
    }
}

__global__ __launch_bounds__(512) void epilogue_kernel(
        const float* __restrict__ z, const float* __restrict__ cb,
        const int* __restrict__ idxArr, float* __restrict__ out) {
    int tid = threadIdx.x;
    int r = tid >> 2, seg = tid & 3;
    int gRow = blockIdx.x * 128 + r;
    int code = idxArr[gRow];
    if (seg == 0) atomicAdd(&out[CS_OFF + code], OMD);
    const float4* cbv = (const float4*)(cb + (long)code * D + seg * 64);
    const float4* zv  = (const float4*)(z + (long)gRow * D + seg * 64);
    float4* qv = (float4*)(out + Q_OFF + (long)gRow * D + seg * 64);
    float*  er = out + EMB_OFF + (long)code * D + seg * 64;
#pragma unroll 4
    for (int i = 0; i < 16; ++i) {
        float4 cv = cbv[i];
        qv[i] = cv;
        float4 zt = zv[i];
        atomicAdd(&er[i * 4 + 0], OMD * zt.x);
        atomicAdd(&er[i * 4 + 1], OMD * zt.y);
        atomicAdd(&er[i * 4 + 2], OMD * zt.z);
        atomicAdd(&er[i * 4 + 3], OMD * zt.w);
    }
}

__global__ void reduce_n(const float* __restrict__ out_cs, float* __restrict__ nacc) {
    int i = blockIdx.x * 256 + threadIdx.x;
    float v = out_cs[i];
    for (int off = 32; off; off >>= 1) v += __shfl_xor(v, off);
    __shared__ float wsum[4];
    int lane = threadIdx.x & 63, w = threadIdx.x >> 6;
    if (lane == 0) wsum[w] = v;
    __syncthreads();
    if (threadIdx.x == 0) atomicAdd(nacc, wsum[0] + wsum[1] + wsum[2] + wsum[3]);
}

__global__ void finalize_kernel(const float* __restrict__ nacc, float* __restrict__ out) {
    int k = blockIdx.x, d = threadIdx.x;
    float n = *nacc;
    float ncs = out[CS_OFF + k];
    float smoothed = (ncs + EPS) / (n + (float)K * EPS) * n;
    out[CB_OFF + (long)k * D + d] = out[EMB_OFF + (long)k * D + d] / smoothed;
}

extern "C" void kernel_launch(void* const* d_in, const int* in_sizes, int n_in,
                              void* d_out, int out_size, void* d_ws, size_t ws_size,
                              hipStream_t stream) {
    const float* z   = (const float*)d_in[0];
    const float* cb  = (const float*)d_in[1];
    const float* emb = (const float*)d_in[2];
    const float* cs  = (const float*)d_in[3];
    float* out = (float*)d_out;
    char* ws = (char*)d_ws;

    ulonglong2* tops = (ulonglong2*)(ws + WS_TOPS);
    unsigned long long* resolved = (unsigned long long*)(ws + WS_RES);
    int* idxArr = (int*)(ws + WS_IDX);
    float* c2 = (float*)(ws + WS_C2);
    int* flagRows = (int*)(ws + WS_FLAG);
    unsigned* flagCount = (unsigned*)(ws + WS_CNT);
    float* nacc = (float*)(ws + WS_CNT) + 1;

    init_kernel<<<(K * D / 4 + 255) / 256, 256, 0, stream>>>(emb, cs, out, ws);
    c2_kernel<<<K, 64, 0, stream>>>(cb, c2);
    dim3 ggrid(N / BMt, KSPLIT);
    gemm_kernel<<<ggrid, GT, 0, stream>>>(z, cb, c2, tops);
    merge_kernel<<<N / 256, 256, 0, stream>>>(tops, out, idxArr, flagCount, flagRows);
    dim3 rgrid(RSL, RKS);
    resolve_kernel<<<rgrid, 512, 0, stream>>>(z, cb, c2, flagCount, flagRows, resolved);
    writeback_kernel<<<N / 256, 256, 0, stream>>>(flagCount, flagRows, resolved, idxArr, out);
    epilogue_kernel<<<N / 128, 512, 0, stream>>>(z, cb, idxArr, out);
    reduce_n<<<K / 256, 256, 0, stream>>>(out + CS_OFF, nacc);
    finalize_kernel<<<K, 256, 0, stream>>>(nacc, out);
}

// Round 7
// 656.938 us; speedup vs baseline: 4.7523x; 1.6195x over previous
//
#include <hip/hip_runtime.h>

// EMA codebook update (VQ-VAE), MI355X. fp16-MFMA distance filter + exact
// fp32 rescore for near-ties. N=32768, K=8192, D=256.
// R7: epilogue atomics eliminated — counting-sort by code + per-code
//     gather-reduce (one wave/code), atomic-free embedding & quantized writes.

#define DECAY 0.99f
#define OMD 0.01f
#define EPS 1e-5f
#define DELTA 0.3f

constexpr int N = 32768, K = 8192, D = 256;
constexpr int KSPLIT = 2;               // gemm grid: 128 row-tiles x 2 code-splits
constexpr int BMt = 256, BNt = 128;     // gemm tile
constexpr int GT = 512;                 // gemm threads (8 waves)

// resolve config (R2-style tile)
constexpr int RBM = 128;                // flagged rows per group
constexpr int RBN = 128;                // code tile per kb step
constexpr int RKS = 32;                 // K splits (256 codes each)
constexpr int RSL = 32;                 // group slots
constexpr int RDC = 32;                 // d-chunk

typedef _Float16 f16x8 __attribute__((ext_vector_type(8)));
typedef float f32x4 __attribute__((ext_vector_type(4)));

// d_out layout (floats, reference return order)
constexpr long Q_OFF   = 0;
constexpr long IDX_OFF = (long)N * D;
constexpr long CB_OFF  = IDX_OFF + N;
constexpr long EMB_OFF = CB_OFF + (long)K * D;
constexpr long CS_OFF  = EMB_OFF + (long)K * D;

// ws layout (bytes)
constexpr long WS_TOPS = 0;                          // ulonglong2[N*KSPLIT]
constexpr long WS_RES  = WS_TOPS + (long)N * 2 * 16; // u64[N] resolved
constexpr long WS_IDX  = WS_RES + (long)N * 8;       // int[N]
constexpr long WS_C2   = WS_IDX + (long)N * 4;       // float[K]
constexpr long WS_FLAG = WS_C2 + (long)K * 4;        // int[N] flagged rows
constexpr long WS_CNT  = WS_FLAG + (long)N * 4;      // [0] u32 count, [1] f32 nacc
constexpr long WS_CNTS = WS_CNT + 8;                 // int[K] histogram
constexpr long WS_CUR  = WS_CNTS + (long)K * 4;      // int[K] scan/cursor
constexpr long WS_SORT = WS_CUR + (long)K * 4;       // int[N] rows sorted by code

__device__ inline unsigned transScore(float s) {
    unsigned u = __float_as_uint(s);
    return u ^ ((unsigned)((int)u >> 31) | 0x80000000u);   // order-preserving
}
__device__ inline float untransScore(unsigned u) {
    return (u & 0x80000000u) ? __uint_as_float(u ^ 0x80000000u)
                             : __uint_as_float(~u);
}

__global__ void init_kernel(char* __restrict__ ws) {
    int i = blockIdx.x * blockDim.x + threadIdx.x;   // grid covers N
    if (i < N) ((unsigned long long*)(ws + WS_RES))[i] = ~0ull;
    if (i < K) ((int*)(ws + WS_CNTS))[i] = 0;
    if (i == 0) {
        ((unsigned*)(ws + WS_CNT))[0] = 0u;
        ((float*)(ws + WS_CNT))[1] = 0.f;
    }
}

__global__ void c2_kernel(const float* __restrict__ cb, float* __restrict__ c2) {
    int k = blockIdx.x;
    int lane = threadIdx.x;
    const float4* row = (const float4*)(cb + (long)k * D);
    float4 v = row[lane];
    float s = v.x * v.x + v.y * v.y + v.z * v.z + v.w * v.w;
    for (int off = 32; off; off >>= 1) s += __shfl_xor(s, off);
    if (lane == 0) c2[k] = s;
}

// ---------------- fp16 MFMA distance GEMM with top-2 tracking ----------------
__global__ __launch_bounds__(GT, 2) void gemm_kernel(
        const float* __restrict__ z, const float* __restrict__ cb,
        const float* __restrict__ c2, ulonglong2* __restrict__ tops) {
    __shared__ _Float16 As[BMt * 256];          // 128 KB, swizzled
    __shared__ _Float16 Bs[2][BNt * 32];        // 2 x 8 KB, swizzled
    __shared__ float c2s[BNt];
    __shared__ unsigned long long L1[BMt];      // block-level top1 (score|idx)
    __shared__ unsigned L2s[BMt];               // block-level top2 score

    const int tid = threadIdx.x;
    const int lane = tid & 63;
    const int wave = tid >> 6;                  // 8 waves: 4(M) x 2(N)
    const int wm = wave >> 1, wn = wave & 1;
    const long rowBase = (long)blockIdx.x * BMt;
    const int kbase = blockIdx.y * (K / KSPLIT);

    // ---- stage A (z rows) once: fp32 -> fp16, swizzled ----
    for (int i = 0; i < 16; ++i) {
        int id = tid + i * GT;                  // 8192 chunks of 8 floats
        int r = id >> 5, dseg = (id & 31) * 8;
        const float4* src = (const float4*)(z + (rowBase + r) * D + dseg);
        float4 v0 = src[0], v1 = src[1];
        union { _Float16 h[8]; ulonglong2 u; } t;
        t.h[0] = (_Float16)v0.x; t.h[1] = (_Float16)v0.y;
        t.h[2] = (_Float16)v0.z; t.h[3] = (_Float16)v0.w;
        t.h[4] = (_Float16)v1.x; t.h[5] = (_Float16)v1.y;
        t.h[6] = (_Float16)v1.z; t.h[7] = (_Float16)v1.w;
        int byte = (r * 256 + dseg) * 2;
        byte ^= (r & 7) << 4;
        *(ulonglong2*)((char*)As + byte) = t.u;
    }
    // stage B chunk 0
    {
        int c = tid >> 2, dseg = (tid & 3) * 8;
        const float* s = cb + (long)(kbase + c) * D + dseg;
        float4 b0 = *(const float4*)s, b1 = *((const float4*)s + 1);
        union { _Float16 h[8]; ulonglong2 u; } t;
        t.h[0] = (_Float16)b0.x; t.h[1] = (_Float16)b0.y;
        t.h[2] = (_Float16)b0.z; t.h[3] = (_Float16)b0.w;
        t.h[4] = (_Float16)b1.x; t.h[5] = (_Float16)b1.y;
        t.h[6] = (_Float16)b1.z; t.h[7] = (_Float16)b1.w;
        int byte = (c * 32 + dseg) * 2;
        byte ^= (c & 7) << 4;
        *(ulonglong2*)((char*)&Bs[0][0] + byte) = t.u;
    }
    if (tid < BNt) c2s[tid] = c2[kbase + tid];
    if (tid < BMt) { L1[tid] = ~0ull; L2s[tid] = 0xFFFFFFFFu; }
    __syncthreads();

    // per-thread A/B frag byte offsets. A: xor applied AFTER adding dc.
    int aBase[4], aSwz[4], bOff[4];
#pragma unroll
    for (int fr = 0; fr < 4; ++fr) {
        int r = wm * 64 + fr * 16 + (lane & 15);
        aBase[fr] = r * 512 + (lane >> 4) * 16;
        aSwz[fr] = (r & 7) << 4;
    }
#pragma unroll
    for (int fc = 0; fc < 4; ++fc) {
        int c = wn * 64 + fc * 16 + (lane & 15);
        int byte = c * 64 + (lane >> 4) * 16;
        bOff[fc] = byte ^ ((c & 7) << 4);
    }

    f32x4 acc[4][4];
    unsigned long long t1[16];
    unsigned t2[16];
#pragma unroll
    for (int s = 0; s < 16; ++s) { t1[s] = ~0ull; t2[s] = 0xFFFFFFFFu; }
    float c2v[4];

    const int NCH = (K / KSPLIT / BNt) * 8;      // 256 chunks
    for (int j = 0; j < NCH; ++j) {
        const int kb = j >> 3, dcI = j & 7, dc = dcI * 32;
        const int cur = j & 1;
        // prefetch next chunk (global -> regs)
        float4 p0, p1;
        const bool pf = (j + 1 < NCH);
        if (pf) {
            int jj = j + 1;
            int c = tid >> 2, dseg = (tid & 3) * 8;
            const float* s = cb + (long)(kbase + (jj >> 3) * BNt + c) * D
                             + (jj & 7) * 32 + dseg;
            p0 = *(const float4*)s; p1 = *((const float4*)s + 1);
        }
        // compute current chunk
        if (dcI == 0) {
#pragma unroll
            for (int a = 0; a < 4; ++a)
#pragma unroll
                for (int b = 0; b < 4; ++b) acc[a][b] = (f32x4)0.f;
#pragma unroll
            for (int fc = 0; fc < 4; ++fc)
                c2v[fc] = c2s[wn * 64 + fc * 16 + (lane & 15)];
        }
        f16x8 aF[4], bF[4];
#pragma unroll
        for (int fr = 0; fr < 4; ++fr)
            aF[fr] = *(const f16x8*)((const char*)As +
                        ((aBase[fr] + dc * 2) ^ aSwz[fr]));
#pragma unroll
        for (int fc = 0; fc < 4; ++fc)
            bF[fc] = *(const f16x8*)((const char*)&Bs[cur][0] + bOff[fc]);
#pragma unroll
        for (int fr = 0; fr < 4; ++fr)
#pragma unroll
            for (int fc = 0; fc < 4; ++fc)
                acc[fr][fc] = __builtin_amdgcn_mfma_f32_16x16x32_f16(
                    aF[fr], bF[fc], acc[fr][fc], 0, 0, 0);
        if (dcI == 7) {
            // score + top2 update
#pragma unroll
            for (int fc = 0; fc < 4; ++fc) {
                int gcol = kbase + kb * BNt + wn * 64 + fc * 16 + (lane & 15);
#pragma unroll
                for (int fr = 0; fr < 4; ++fr)
#pragma unroll
                    for (int r = 0; r < 4; ++r) {
                        float s = fmaf(-2.f, acc[fr][fc][r], c2v[fc]);
                        unsigned su = transScore(s);
                        unsigned long long u =
                            ((unsigned long long)su << 32) | (unsigned)gcol;
                        int slot = fr * 4 + r;
                        unsigned old1 = (unsigned)(t1[slot] >> 32);
                        t1[slot] = u < t1[slot] ? u : t1[slot];
                        unsigned mx = su > old1 ? su : old1;
                        t2[slot] = t2[slot] < mx ? t2[slot] : mx;
                    }
            }
        }
        __syncthreads();             // everyone done reading Bs[cur]/c2s
        if (pf) {
            int jj = j + 1;
            int c = tid >> 2, dseg = (tid & 3) * 8;
            union { _Float16 h[8]; ulonglong2 u; } t;
            t.h[0] = (_Float16)p0.x; t.h[1] = (_Float16)p0.y;
            t.h[2] = (_Float16)p0.z; t.h[3] = (_Float16)p0.w;
            t.h[4] = (_Float16)p1.x; t.h[5] = (_Float16)p1.y;
            t.h[6] = (_Float16)p1.z; t.h[7] = (_Float16)p1.w;
            int byte = (c * 32 + dseg) * 2;
            byte ^= (c & 7) << 4;
            *(ulonglong2*)((char*)&Bs[cur ^ 1][0] + byte) = t.u;
            if ((jj & 7) == 0 && tid < BNt)     // new kb: stage its c2
                c2s[tid] = c2[kbase + (jj >> 3) * BNt + tid];
        }
        __syncthreads();
    }

    // intra-wave top2 merge over the 16 lanes sharing each row
#pragma unroll
    for (int m = 1; m < 16; m <<= 1) {
#pragma unroll
        for (int s = 0; s < 16; ++s) {
            unsigned long long o1 = __shfl_xor(t1[s], m);
            unsigned o2 = (unsigned)__shfl_xor((int)t2[s], m);
            unsigned a1 = (unsigned)(t1[s] >> 32), b1 = (unsigned)(o1 >> 32);
            unsigned mx = a1 > b1 ? a1 : b1;
            unsigned nt2 = t2[s] < o2 ? t2[s] : o2;
            nt2 = nt2 < mx ? nt2 : mx;
            t1[s] = o1 < t1[s] ? o1 : t1[s];
            t2[s] = nt2;
        }
    }
    // cross-wave (wn=0/1) top2 merge via LDS atomicMin-displacement
    if ((lane & 15) == 0) {
#pragma unroll
        for (int s = 0; s < 16; ++s) {
            int row = wm * 64 + (s >> 2) * 16 + (lane >> 4) * 4 + (s & 3);
            unsigned long long old1 = atomicMin(&L1[row], t1[s]);
            unsigned long long cand = t1[s] < old1 ? old1 : t1[s];
            atomicMin(&L2s[row], (unsigned)(cand >> 32));
            atomicMin(&L2s[row], t2[s]);
        }
    }
    __syncthreads();
    if (tid < BMt) {
        ulonglong2 v; v.x = L1[tid]; v.y = (unsigned long long)L2s[tid];
        tops[(rowBase + tid) * KSPLIT + blockIdx.y] = v;
    }
}

__global__ void merge_kernel(const ulonglong2* __restrict__ tops,
                             float* __restrict__ out, int* __restrict__ idxArr,
                             unsigned* __restrict__ flagCount,
                             int* __restrict__ flagRows) {
    int row = blockIdx.x * 256 + threadIdx.x;
    ulonglong2 a = tops[row * 2], b = tops[row * 2 + 1];
    unsigned long long t1 = a.x < b.x ? a.x : b.x;
    unsigned a1 = (unsigned)(a.x >> 32), b1 = (unsigned)(b.x >> 32);
    unsigned mx = a1 > b1 ? a1 : b1;
    unsigned t2 = (unsigned)a.y < (unsigned)b.y ? (unsigned)a.y : (unsigned)b.y;
    t2 = t2 < mx ? t2 : mx;
    float s1 = untransScore((unsigned)(t1 >> 32));
    float s2 = untransScore(t2);
    int idx = (int)(t1 & 0xFFFFFFFFull);
    idxArr[row] = idx;
    out[IDX_OFF + row] = (float)idx;
    if (s2 - s1 <= DELTA) {
        unsigned p = atomicAdd(flagCount, 1u);
        flagRows[p] = row;
    }
}

// exact fp32 rescore of flagged rows. Grid = (RSL group slots, RKS K-splits).
__global__ __launch_bounds__(512) void resolve_kernel(
        const float* __restrict__ z, const float* __restrict__ cb,
        const float* __restrict__ c2, const unsigned* __restrict__ flagCount,
        const int* __restrict__ flagRows, unsigned long long* __restrict__ resolved) {
    __shared__ float zT[RDC][RBM + 4];
    __shared__ float cT[RDC][RBN + 4];
    __shared__ float c2s[RBN];
    __shared__ int rid[RBM];

    const int cnt = (int)*flagCount;
    const int tid = threadIdx.x;
    const int tx = tid & 31, ty = tid >> 5;
    const int rbase = ty * 8, cbase = tx * 4;
    const int k0 = blockIdx.y * (K / RKS);          // 256 codes per split

    for (int g = blockIdx.x; g * RBM < cnt; g += RSL) {
        __syncthreads();                // previous iteration fully done
        if (tid < RBM) {
            int fi = g * RBM + tid;
            rid[tid] = flagRows[fi < cnt ? fi : cnt - 1];   // pad = dup row (harmless)
        }

        float bestV[8]; int bestI[8];
#pragma unroll
        for (int r = 0; r < 8; ++r) { bestV[r] = 3.4e38f; bestI[r] = 0; }

        for (int kb = k0; kb < k0 + K / RKS; kb += RBN) {   // 2 iterations
            __syncthreads();            // prior score-phase reads of c2s done
            if (tid < RBN) c2s[tid] = c2[kb + tid];

            float acc[8][4];
#pragma unroll
            for (int r = 0; r < 8; ++r)
#pragma unroll
                for (int c = 0; c < 4; ++c) acc[r][c] = 0.f;

            for (int dc = 0; dc < D; dc += RDC) {
                __syncthreads();        // prior compute reads of zT/cT done
#pragma unroll
                for (int s = 0; s < 2; ++s) {
                    int f = tid + s * 512;          // 1024 float4 slots
                    int row = f >> 3, dq = f & 7;
                    float4 v = *(const float4*)(z + (long)rid[row] * D + dc + dq * 4);
                    zT[dq * 4 + 0][row] = v.x; zT[dq * 4 + 1][row] = v.y;
                    zT[dq * 4 + 2][row] = v.z; zT[dq * 4 + 3][row] = v.w;
                    float4 w = *(const float4*)(cb + (long)(kb + row) * D + dc + dq * 4);
                    cT[dq * 4 + 0][row] = w.x; cT[dq * 4 + 1][row] = w.y;
                    cT[dq * 4 + 2][row] = w.z; cT[dq * 4 + 3][row] = w.w;
                }
                __syncthreads();
#pragma unroll
                for (int d = 0; d < RDC; ++d) {
                    float a[8], b[4];
                    *(float4*)&a[0] = *(const float4*)&zT[d][rbase];
                    *(float4*)&a[4] = *(const float4*)&zT[d][rbase + 4];
                    *(float4*)&b[0] = *(const float4*)&cT[d][cbase];
#pragma unroll
                    for (int r = 0; r < 8; ++r)
#pragma unroll
                        for (int c = 0; c < 4; ++c)
                            acc[r][c] = fmaf(a[r], b[c], acc[r][c]);
                }
            }
            // score phase: c2 - 2*zc (z2 row-constant, argmin-invariant)
#pragma unroll
            for (int c = 0; c < 4; ++c) {
                float cc = c2s[cbase + c];
                int col = kb + cbase + c;
#pragma unroll
                for (int r = 0; r < 8; ++r) {
                    float score = fmaf(-2.f, acc[r][c], cc);
                    if (score < bestV[r]) { bestV[r] = score; bestI[r] = col; }
                }
            }
        }
        // reduce across the 32 tx-lanes sharing rows; first-index ties
#pragma unroll
        for (int off = 16; off; off >>= 1) {
#pragma unroll
            for (int r = 0; r < 8; ++r) {
                float ov = __shfl_xor(bestV[r], off);
                int   oi = __shfl_xor(bestI[r], off);
                if (ov < bestV[r] || (ov == bestV[r] && oi < bestI[r])) {
                    bestV[r] = ov; bestI[r] = oi;
                }
            }
        }
        if (tx == 0) {
#pragma unroll
            for (int r = 0; r < 8; ++r) {
                unsigned long long u =
                    ((unsigned long long)transScore(bestV[r]) << 32)
                    | (unsigned)bestI[r];
                atomicMin(&resolved[rid[rbase + r]], u);
            }
        }
    }
}

__global__ void writeback_kernel(const unsigned* __restrict__ flagCount,
                                 const int* __restrict__ flagRows,
                                 const unsigned long long* __restrict__ resolved,
                                 int* __restrict__ idxArr, float* __restrict__ out) {
    int i = blockIdx.x * 256 + threadIdx.x;
    if (i < (int)*flagCount) {
        int row = flagRows[i];
        int idx = (int)(resolved[row] & 0xFFFFFFFFull);
        idxArr[row] = idx;
        out[IDX_OFF + row] = (float)idx;
    }
}

// ---- counting-sort epilogue (atomic-free heavy writes) ----
__global__ void count_kernel(const int* __restrict__ idxArr, int* __restrict__ counts) {
    int row = blockIdx.x * 256 + threadIdx.x;
    atomicAdd(&counts[idxArr[row]], 1);
}

// single block, 1024 threads: exclusive scan of counts -> cursor, CS output
__global__ __launch_bounds__(1024) void scan_kernel(
        const int* __restrict__ counts, const float* __restrict__ cs,
        int* __restrict__ cursor, float* __restrict__ out) {
    __shared__ int s[1024];
    int tid = threadIdx.x;
    int base = tid * 8;                 // 8192 / 1024
    int local[8]; int sum = 0;
#pragma unroll
    for (int i = 0; i < 8; ++i) { local[i] = counts[base + i]; sum += local[i]; }
    s[tid] = sum;
    __syncthreads();
    for (int off = 1; off < 1024; off <<= 1) {
        int v = (tid >= off) ? s[tid - off] : 0;
        __syncthreads();
        s[tid] += v;
        __syncthreads();
    }
    int run = s[tid] - sum;             // exclusive prefix of this chunk
#pragma unroll
    for (int i = 0; i < 8; ++i) {
        cursor[base + i] = run;
        out[CS_OFF + base + i] = cs[base + i] * DECAY + OMD * (float)local[i];
        run += local[i];
    }
}

__global__ void scatter_kernel(const int* __restrict__ idxArr,
                               int* __restrict__ cursor, int* __restrict__ sorted) {
    int row = blockIdx.x * 256 + threadIdx.x;
    int pos = atomicAdd(&cursor[idxArr[row]], 1);
    sorted[pos] = row;
}

// one wave per code: gather-sum its rows, single write of new_embedding_avg
__global__ __launch_bounds__(256) void gather_sum_kernel(
        const float* __restrict__ z, const float* __restrict__ emb,
        const int* __restrict__ sorted, const int* __restrict__ cursor,
        const int* __restrict__ counts, float* __restrict__ out) {
    int k = blockIdx.x * 4 + (threadIdx.x >> 6);
    int lane = threadIdx.x & 63;
    int cnt = counts[k];
    int start = cursor[k] - cnt;        // cursor was advanced by scatter
    float4 s = {0.f, 0.f, 0.f, 0.f};
    for (int i = 0; i < cnt; ++i) {
        int row = sorted[start + i];
        float4 v = *(const float4*)(z + (long)row * D + lane * 4);
        s.x += v.x; s.y += v.y; s.z += v.z; s.w += v.w;
    }
    float4 e = *(const float4*)(emb + (long)k * D + lane * 4);
    float4 o;
    o.x = e.x * DECAY + OMD * s.x;
    o.y = e.y * DECAY + OMD * s.y;
    o.z = e.z * DECAY + OMD * s.z;
    o.w = e.w * DECAY + OMD * s.w;
    *(float4*)(out + EMB_OFF + (long)k * D + lane * 4) = o;
}

__global__ __launch_bounds__(512) void quantize_kernel(
        const float* __restrict__ cb, const int* __restrict__ idxArr,
        float* __restrict__ out) {
    int tid = threadIdx.x;
    int r = tid >> 2, seg = tid & 3;
    int gRow = blockIdx.x * 128 + r;
    int code = idxArr[gRow];
    const float4* cbv = (const float4*)(cb + (long)code * D + seg * 64);
    float4* qv = (float4*)(out + Q_OFF + (long)gRow * D + seg * 64);
#pragma unroll 4
    for (int i = 0; i < 16; ++i) qv[i] = cbv[i];
}

__global__ void reduce_n(const float* __restrict__ out_cs, float* __restrict__ nacc) {
    int i = blockIdx.x * 256 + threadIdx.x;
    float v = out_cs[i];
    for (int off = 32; off; off >>= 1) v += __shfl_xor(v, off);
    __shared__ float wsum[4];
    int lane = threadIdx.x & 63, w = threadIdx.x >> 6;
    if (lane == 0) wsum[w] = v;
    __syncthreads();
    if (threadIdx.x == 0) atomicAdd(nacc, wsum[0] + wsum[1] + wsum[2] + wsum[3]);
}

__global__ void finalize_kernel(const float* __restrict__ nacc, float* __restrict__ out) {
    int k = blockIdx.x, d = threadIdx.x;
    float n = *nacc;
    float ncs = out[CS_OFF + k];
    float smoothed = (ncs + EPS) / (n + (float)K * EPS) * n;
    out[CB_OFF + (long)k * D + d] = out[EMB_OFF + (long)k * D + d] / smoothed;
}

extern "C" void kernel_launch(void* const* d_in, const int* in_sizes, int n_in,
                              void* d_out, int out_size, void* d_ws, size_t ws_size,
                              hipStream_t stream) {
    const float* z   = (const float*)d_in[0];
    const float* cb  = (const float*)d_in[1];
    const float* emb = (const float*)d_in[2];
    const float* cs  = (const float*)d_in[3];
    float* out = (float*)d_out;
    char* ws = (char*)d_ws;

    ulonglong2* tops = (ulonglong2*)(ws + WS_TOPS);
    unsigned long long* resolved = (unsigned long long*)(ws + WS_RES);
    int* idxArr = (int*)(ws + WS_IDX);
    float* c2 = (float*)(ws + WS_C2);
    int* flagRows = (int*)(ws + WS_FLAG);
    unsigned* flagCount = (unsigned*)(ws + WS_CNT);
    float* nacc = (float*)(ws + WS_CNT) + 1;
    int* counts = (int*)(ws + WS_CNTS);
    int* cursor = (int*)(ws + WS_CUR);
    int* sorted = (int*)(ws + WS_SORT);

    init_kernel<<<N / 256, 256, 0, stream>>>(ws);
    c2_kernel<<<K, 64, 0, stream>>>(cb, c2);
    dim3 ggrid(N / BMt, KSPLIT);
    gemm_kernel<<<ggrid, GT, 0, stream>>>(z, cb, c2, tops);
    merge_kernel<<<N / 256, 256, 0, stream>>>(tops, out, idxArr, flagCount, flagRows);
    dim3 rgrid(RSL, RKS);
    resolve_kernel<<<rgrid, 512, 0, stream>>>(z, cb, c2, flagCount, flagRows, resolved);
    writeback_kernel<<<N / 256, 256, 0, stream>>>(flagCount, flagRows, resolved, idxArr, out);
    count_kernel<<<N / 256, 256, 0, stream>>>(idxArr, counts);
    scan_kernel<<<1, 1024, 0, stream>>>(counts, cs, cursor, out);
    scatter_kernel<<<N / 256, 256, 0, stream>>>(idxArr, cursor, sorted);
    gather_sum_kernel<<<K / 4, 256, 0, stream>>>(z, emb, sorted, cursor, counts, out);
    reduce_n<<<K / 256, 256, 0, stream>>>(out + CS_OFF, nacc);
    finalize_kernel<<<K, 256, 0, stream>>>(nacc, out);
    quantize_kernel<<<N / 128, 512, 0, stream>>>(cb, idxArr, out);
}

// Round 8
// 643.534 us; speedup vs baseline: 4.8513x; 1.0208x over previous
//
#include <hip/hip_runtime.h>

// EMA codebook update (VQ-VAE), MI355X. fp16-MFMA distance filter + exact
// fp32 rescore for near-ties. N=32768, K=8192, D=256.
// R8: gemm B-staging via global_load_lds (pre-converted fp16 codebook in
//     d_out scratch, pre-swizzled per-lane source); float top-2 tracking
//     (5 VALU/score); 1 barrier/chunk; c2s LDS dropped. Tail unchanged.

#define DECAY 0.99f
#define OMD 0.01f
#define EPS 1e-5f
#define DELTA 0.3f

constexpr int N = 32768, K = 8192, D = 256;
constexpr int KSPLIT = 2;               // gemm grid: 128 row-tiles x 2 code-splits
constexpr int BMt = 256, BNt = 128;     // gemm tile
constexpr int GT = 512;                 // gemm threads (8 waves)

// resolve config (R2-style tile)
constexpr int RBM = 128;                // flagged rows per group
constexpr int RBN = 128;                // code tile per kb step
constexpr int RKS = 32;                 // K splits (256 codes each)
constexpr int RSL = 32;                 // group slots
constexpr int RDC = 32;                 // d-chunk

typedef _Float16 f16x8 __attribute__((ext_vector_type(8)));
typedef float f32x4 __attribute__((ext_vector_type(4)));

// d_out layout (floats, reference return order)
constexpr long Q_OFF   = 0;
constexpr long IDX_OFF = (long)N * D;
constexpr long CB_OFF  = IDX_OFF + N;
constexpr long EMB_OFF = CB_OFF + (long)K * D;
constexpr long CS_OFF  = EMB_OFF + (long)K * D;

// ws layout (bytes)
constexpr long WS_TOPS = 0;                          // ulonglong2[N*KSPLIT]
constexpr long WS_RES  = WS_TOPS + (long)N * 2 * 16; // u64[N] resolved
constexpr long WS_IDX  = WS_RES + (long)N * 8;       // int[N]
constexpr long WS_C2   = WS_IDX + (long)N * 4;       // float[K]
constexpr long WS_FLAG = WS_C2 + (long)K * 4;        // int[N] flagged rows
constexpr long WS_CNT  = WS_FLAG + (long)N * 4;      // [0] u32 count, [1] f32 nacc
constexpr long WS_CNTS = WS_CNT + 8;                 // int[K] histogram
constexpr long WS_CUR  = WS_CNTS + (long)K * 4;      // int[K] scan/cursor
constexpr long WS_SORT = WS_CUR + (long)K * 4;       // int[N] rows sorted by code

#define GLOAD_LDS16(g, l) __builtin_amdgcn_global_load_lds(                    \
    (const __attribute__((address_space(1))) void*)(g),                        \
    (__attribute__((address_space(3))) void*)(l), 16, 0, 0)

__device__ inline unsigned transScore(float s) {
    unsigned u = __float_as_uint(s);
    return u ^ ((unsigned)((int)u >> 31) | 0x80000000u);   // order-preserving
}
__device__ inline float untransScore(unsigned u) {
    return (u & 0x80000000u) ? __uint_as_float(u ^ 0x80000000u)
                             : __uint_as_float(~u);
}

__global__ void init_kernel(char* __restrict__ ws) {
    int i = blockIdx.x * blockDim.x + threadIdx.x;   // grid covers N
    if (i < N) ((unsigned long long*)(ws + WS_RES))[i] = ~0ull;
    if (i < K) ((int*)(ws + WS_CNTS))[i] = 0;
    if (i == 0) {
        ((unsigned*)(ws + WS_CNT))[0] = 0u;
        ((float*)(ws + WS_CNT))[1] = 0.f;
    }
}

// codebook fp32 -> fp16 (written into d_out Q region scratch; quantize_kernel
// overwrites it at the very end of the launch sequence)
__global__ void cvt_cb16(const float* __restrict__ cb, _Float16* __restrict__ cb16) {
    int i = blockIdx.x * 256 + threadIdx.x;          // K*D/8 chunks of 8
    const float4* s = (const float4*)cb + (long)i * 2;
    float4 a = s[0], b = s[1];
    union { _Float16 h[8]; ulonglong2 u; } t;
    t.h[0] = (_Float16)a.x; t.h[1] = (_Float16)a.y;
    t.h[2] = (_Float16)a.z; t.h[3] = (_Float16)a.w;
    t.h[4] = (_Float16)b.x; t.h[5] = (_Float16)b.y;
    t.h[6] = (_Float16)b.z; t.h[7] = (_Float16)b.w;
    *(ulonglong2*)(cb16 + (long)i * 8) = t.u;
}

__global__ void c2_kernel(const float* __restrict__ cb, float* __restrict__ c2) {
    int k = blockIdx.x;
    int lane = threadIdx.x;
    const float4* row = (const float4*)(cb + (long)k * D);
    float4 v = row[lane];
    float s = v.x * v.x + v.y * v.y + v.z * v.z + v.w * v.w;
    for (int off = 32; off; off >>= 1) s += __shfl_xor(s, off);
    if (lane == 0) c2[k] = s;
}

// ---------------- fp16 MFMA distance GEMM with top-2 tracking ----------------
__global__ __launch_bounds__(GT, 2) void gemm_kernel(
        const float* __restrict__ z, const _Float16* __restrict__ cb16,
        const float* __restrict__ c2, ulonglong2* __restrict__ tops) {
    __shared__ _Float16 As[BMt * 256];          // 128 KB, swizzled
    __shared__ _Float16 Bs[2][BNt * 32];        // 2 x 8 KB, swizzled
    __shared__ unsigned long long L1[BMt];      // block-level top1 (score|idx)
    __shared__ unsigned L2s[BMt];               // block-level top2 score

    const int tid = threadIdx.x;
    const int lane = tid & 63;
    const int wave = tid >> 6;                  // 8 waves: 4(M) x 2(N)
    const int wm = wave >> 1, wn = wave & 1;
    const long rowBase = (long)blockIdx.x * BMt;
    const int kbase = blockIdx.y * (K / KSPLIT);

    // ---- stage A (z rows) once: fp32 -> fp16, swizzled (validated layout) ----
    for (int i = 0; i < 16; ++i) {
        int id = tid + i * GT;                  // 8192 chunks of 8 floats
        int r = id >> 5, dseg = (id & 31) * 8;
        const float4* src = (const float4*)(z + (rowBase + r) * D + dseg);
        float4 v0 = src[0], v1 = src[1];
        union { _Float16 h[8]; ulonglong2 u; } t;
        t.h[0] = (_Float16)v0.x; t.h[1] = (_Float16)v0.y;
        t.h[2] = (_Float16)v0.z; t.h[3] = (_Float16)v0.w;
        t.h[4] = (_Float16)v1.x; t.h[5] = (_Float16)v1.y;
        t.h[6] = (_Float16)v1.z; t.h[7] = (_Float16)v1.w;
        int byte = (r * 256 + dseg) * 2;
        byte ^= (r & 7) << 4;
        *(ulonglong2*)((char*)As + byte) = t.u;
    }

    // ---- per-thread B-staging slot: inverse of the LDS read swizzle ----
    // LDS linear 16B-chunk q = tid holds tile content (bc, halves bt*8..bt*8+7)
    // where chunk_addr(c,t) = c*4 + t XOR (c&7 on low 3 bits).
    int bc, bt;
    {
        int h = tid >> 3, rr = tid & 7;
        bc = 2 * h; bt = rr ^ (bc & 7);
        if (bt & 4) { bc++; bt = (rr ^ (bc & 7)) & 3; }
    }
    char* ldsB0 = (char*)&Bs[0][0] + tid * 16;
    char* ldsB1 = (char*)&Bs[1][0] + tid * 16;

    // B chunk 0 (kb=0, dcI=0)
    GLOAD_LDS16(cb16 + ((long)(kbase + bc) << 8) + bt * 8, ldsB0);

    if (tid < BMt) { L1[tid] = ~0ull; L2s[tid] = 0xFFFFFFFFu; }
    __syncthreads();                            // drains vmcnt + LDS writes

    // per-thread A/B frag byte offsets. A: xor applied AFTER adding dc.
    int aBase[4], aSwz[4], bOff[4];
#pragma unroll
    for (int fr = 0; fr < 4; ++fr) {
        int r = wm * 64 + fr * 16 + (lane & 15);
        aBase[fr] = r * 512 + (lane >> 4) * 16;
        aSwz[fr] = (r & 7) << 4;
    }
#pragma unroll
    for (int fc = 0; fc < 4; ++fc) {
        int c = wn * 64 + fc * 16 + (lane & 15);
        int byte = c * 64 + (lane >> 4) * 16;
        bOff[fc] = byte ^ ((c & 7) << 4);
    }

    f32x4 acc[4][4];
    float bV[16], bT2[16];
    int bI[16];
#pragma unroll
    for (int s = 0; s < 16; ++s) { bV[s] = 3.4e38f; bT2[s] = 3.4e38f; bI[s] = 0; }
    float c2v[4];

    const int NCH = (K / KSPLIT / BNt) * 8;      // 256 chunks
    int cur = 0;
    for (int j = 0; j < NCH; ++j) {
        const int kb = j >> 3, dcI = j & 7, dc = dcI * 32;
        // stage next chunk direct-to-LDS (zero VALU beyond address calc)
        if (j + 1 < NCH) {
            int jj = j + 1;
            const _Float16* src = cb16
                + ((long)(kbase + (jj >> 3) * BNt + bc) << 8)
                + (jj & 7) * 32 + bt * 8;
            GLOAD_LDS16(src, cur ? ldsB0 : ldsB1);
        }
        if (dcI == 0) {
#pragma unroll
            for (int a = 0; a < 4; ++a)
#pragma unroll
                for (int b = 0; b < 4; ++b) acc[a][b] = (f32x4)0.f;
#pragma unroll
            for (int fc = 0; fc < 4; ++fc)
                c2v[fc] = c2[kbase + kb * BNt + wn * 64 + fc * 16 + (lane & 15)];
        }
        f16x8 aF[4], bF[4];
#pragma unroll
        for (int fr = 0; fr < 4; ++fr)
            aF[fr] = *(const f16x8*)((const char*)As +
                        ((aBase[fr] + dc * 2) ^ aSwz[fr]));
#pragma unroll
        for (int fc = 0; fc < 4; ++fc)
            bF[fc] = *(const f16x8*)((const char*)&Bs[cur][0] + bOff[fc]);
#pragma unroll
        for (int fr = 0; fr < 4; ++fr)
#pragma unroll
            for (int fc = 0; fc < 4; ++fc)
                acc[fr][fc] = __builtin_amdgcn_mfma_f32_16x16x32_f16(
                    aF[fr], bF[fc], acc[fr][fc], 0, 0, 0);
        if (dcI == 7) {
            // score + float top-2 (5 VALU/score; ties covered by DELTA rescore)
#pragma unroll
            for (int fc = 0; fc < 4; ++fc) {
                int gcol = kbase + kb * BNt + wn * 64 + fc * 16 + (lane & 15);
#pragma unroll
                for (int fr = 0; fr < 4; ++fr)
#pragma unroll
                    for (int r = 0; r < 4; ++r) {
                        float s = fmaf(-2.f, acc[fr][fc][r], c2v[fc]);
                        int slot = fr * 4 + r;
                        float t1o = bV[slot];
                        bT2[slot] = fminf(bT2[slot], fmaxf(s, t1o));
                        bool lt = s < t1o;
                        bV[slot] = lt ? s : t1o;
                        bI[slot] = lt ? gcol : bI[slot];
                    }
            }
        }
        __syncthreads();             // drain stage loads; guard Bs reuse
        cur ^= 1;
    }

    // intra-wave top2 merge over the 16 lanes sharing each row (float domain)
#pragma unroll
    for (int m = 1; m < 16; m <<= 1) {
#pragma unroll
        for (int s = 0; s < 16; ++s) {
            float ov = __shfl_xor(bV[s], m);
            int   oi = __shfl_xor(bI[s], m);
            float o2 = __shfl_xor(bT2[s], m);
            float nt2 = fminf(fminf(bT2[s], o2), fmaxf(bV[s], ov));
            bool take = ov < bV[s];
            bV[s] = take ? ov : bV[s];
            bI[s] = take ? oi : bI[s];
            bT2[s] = nt2;
        }
    }
    // cross-wave (wn=0/1) top2 merge via LDS atomicMin-displacement (packed)
    if ((lane & 15) == 0) {
#pragma unroll
        for (int s = 0; s < 16; ++s) {
            int row = wm * 64 + (s >> 2) * 16 + (lane >> 4) * 4 + (s & 3);
            unsigned long long t1 =
                ((unsigned long long)transScore(bV[s]) << 32) | (unsigned)bI[s];
            unsigned long long old1 = atomicMin(&L1[row], t1);
            unsigned long long cand = t1 < old1 ? old1 : t1;
            atomicMin(&L2s[row], (unsigned)(cand >> 32));
            atomicMin(&L2s[row], transScore(bT2[s]));
        }
    }
    __syncthreads();
    if (tid < BMt) {
        ulonglong2 v; v.x = L1[tid]; v.y = (unsigned long long)L2s[tid];
        tops[(rowBase + tid) * KSPLIT + blockIdx.y] = v;
    }
}

__global__ void merge_kernel(const ulonglong2* __restrict__ tops,
                             float* __restrict__ out, int* __restrict__ idxArr,
                             unsigned* __restrict__ flagCount,
                             int* __restrict__ flagRows) {
    int row = blockIdx.x * 256 + threadIdx.x;
    ulonglong2 a = tops[row * 2], b = tops[row * 2 + 1];
    unsigned long long t1 = a.x < b.x ? a.x : b.x;
    unsigned a1 = (unsigned)(a.x >> 32), b1 = (unsigned)(b.x >> 32);
    unsigned mx = a1 > b1 ? a1 : b1;
    unsigned t2 = (unsigned)a.y < (unsigned)b.y ? (unsigned)a.y : (unsigned)b.y;
    t2 = t2 < mx ? t2 : mx;
    float s1 = untransScore((unsigned)(t1 >> 32));
    float s2 = untransScore(t2);
    int idx = (int)(t1 & 0xFFFFFFFFull);
    idxArr[row] = idx;
    out[IDX_OFF + row] = (float)idx;
    if (s2 - s1 <= DELTA) {
        unsigned p = atomicAdd(flagCount, 1u);
        flagRows[p] = row;
    }
}

// exact fp32 rescore of flagged rows. Grid = (RSL group slots, RKS K-splits).
__global__ __launch_bounds__(512) void resolve_kernel(
        const float* __restrict__ z, const float* __restrict__ cb,
        const float* __restrict__ c2, const unsigned* __restrict__ flagCount,
        const int* __restrict__ flagRows, unsigned long long* __restrict__ resolved) {
    __shared__ float zT[RDC][RBM + 4];
    __shared__ float cT[RDC][RBN + 4];
    __shared__ float c2s[RBN];
    __shared__ int rid[RBM];

    const int cnt = (int)*flagCount;
    const int tid = threadIdx.x;
    const int tx = tid & 31, ty = tid >> 5;
    const int rbase = ty * 8, cbase = tx * 4;
    const int k0 = blockIdx.y * (K / RKS);          // 256 codes per split

    for (int g = blockIdx.x; g * RBM < cnt; g += RSL) {
        __syncthreads();                // previous iteration fully done
        if (tid < RBM) {
            int fi = g * RBM + tid;
            rid[tid] = flagRows[fi < cnt ? fi : cnt - 1];   // pad = dup row (harmless)
        }

        float bestV[8]; int bestI[8];
#pragma unroll
        for (int r = 0; r < 8; ++r) { bestV[r] = 3.4e38f; bestI[r] = 0; }

        for (int kb = k0; kb < k0 + K / RKS; kb += RBN) {   // 2 iterations
            __syncthreads();            // prior score-phase reads of c2s done
            if (tid < RBN) c2s[tid] = c2[kb + tid];

            float acc[8][4];
#pragma unroll
            for (int r = 0; r < 8; ++r)
#pragma unroll
                for (int c = 0; c < 4; ++c) acc[r][c] = 0.f;

            for (int dc = 0; dc < D; dc += RDC) {
                __syncthreads();        // prior compute reads of zT/cT done
#pragma unroll
                for (int s = 0; s < 2; ++s) {
                    int f = tid + s * 512;          // 1024 float4 slots
                    int row = f >> 3, dq = f & 7;
                    float4 v = *(const float4*)(z + (long)rid[row] * D + dc + dq * 4);
                    zT[dq * 4 + 0][row] = v.x; zT[dq * 4 + 1][row] = v.y;
                    zT[dq * 4 + 2][row] = v.z; zT[dq * 4 + 3][row] = v.w;
                    float4 w = *(const float4*)(cb + (long)(kb + row) * D + dc + dq * 4);
                    cT[dq * 4 + 0][row] = w.x; cT[dq * 4 + 1][row] = w.y;
                    cT[dq * 4 + 2][row] = w.z; cT[dq * 4 + 3][row] = w.w;
                }
                __syncthreads();
#pragma unroll
                for (int d = 0; d < RDC; ++d) {
                    float a[8], b[4];
                    *(float4*)&a[0] = *(const float4*)&zT[d][rbase];
                    *(float4*)&a[4] = *(const float4*)&zT[d][rbase + 4];
                    *(float4*)&b[0] = *(const float4*)&cT[d][cbase];
#pragma unroll
                    for (int r = 0; r < 8; ++r)
#pragma unroll
                        for (int c = 0; c < 4; ++c)
                            acc[r][c] = fmaf(a[r], b[c], acc[r][c]);
                }
            }
            // score phase: c2 - 2*zc (z2 row-constant, argmin-invariant)
#pragma unroll
            for (int c = 0; c < 4; ++c) {
                float cc = c2s[cbase + c];
                int col = kb + cbase + c;
#pragma unroll
                for (int r = 0; r < 8; ++r) {
                    float score = fmaf(-2.f, acc[r][c], cc);
                    if (score < bestV[r]) { bestV[r] = score; bestI[r] = col; }
                }
            }
        }
        // reduce across the 32 tx-lanes sharing rows; first-index ties
#pragma unroll
        for (int off = 16; off; off >>= 1) {
#pragma unroll
            for (int r = 0; r < 8; ++r) {
                float ov = __shfl_xor(bestV[r], off);
                int   oi = __shfl_xor(bestI[r], off);
                if (ov < bestV[r] || (ov == bestV[r] && oi < bestI[r])) {
                    bestV[r] = ov; bestI[r] = oi;
                }
            }
        }
        if (tx == 0) {
#pragma unroll
            for (int r = 0; r < 8; ++r) {
                unsigned long long u =
                    ((unsigned long long)transScore(bestV[r]) << 32)
                    | (unsigned)bestI[r];
                atomicMin(&resolved[rid[rbase + r]], u);
            }
        }
    }
}

__global__ void writeback_kernel(const unsigned* __restrict__ flagCount,
                                 const int* __restrict__ flagRows,
                                 const unsigned long long* __restrict__ resolved,
                                 int* __restrict__ idxArr, float* __restrict__ out) {
    int i = blockIdx.x * 256 + threadIdx.x;
    if (i < (int)*flagCount) {
        int row = flagRows[i];
        int idx = (int)(resolved[row] & 0xFFFFFFFFull);
        idxArr[row] = idx;
        out[IDX_OFF + row] = (float)idx;
    }
}

// ---- counting-sort epilogue (atomic-free heavy writes) ----
__global__ void count_kernel(const int* __restrict__ idxArr, int* __restrict__ counts) {
    int row = blockIdx.x * 256 + threadIdx.x;
    atomicAdd(&counts[idxArr[row]], 1);
}

// single block, 1024 threads: exclusive scan of counts -> cursor, CS output
__global__ __launch_bounds__(1024) void scan_kernel(
        const int* __restrict__ counts, const float* __restrict__ cs,
        int* __restrict__ cursor, float* __restrict__ out) {
    __shared__ int s[1024];
    int tid = threadIdx.x;
    int base = tid * 8;                 // 8192 / 1024
    int local[8]; int sum = 0;
#pragma unroll
    for (int i = 0; i < 8; ++i) { local[i] = counts[base + i]; sum += local[i]; }
    s[tid] = sum;
    __syncthreads();
    for (int off = 1; off < 1024; off <<= 1) {
        int v = (tid >= off) ? s[tid - off] : 0;
        __syncthreads();
        s[tid] += v;
        __syncthreads();
    }
    int run = s[tid] - sum;             // exclusive prefix of this chunk
#pragma unroll
    for (int i = 0; i < 8; ++i) {
        cursor[base + i] = run;
        out[CS_OFF + base + i] = cs[base + i] * DECAY + OMD * (float)local[i];
        run += local[i];
    }
}

__global__ void scatter_kernel(const int* __restrict__ idxArr,
                               int* __restrict__ cursor, int* __restrict__ sorted) {
    int row = blockIdx.x * 256 + threadIdx.x;
    int pos = atomicAdd(&cursor[idxArr[row]], 1);
    sorted[pos] = row;
}

// one wave per code: gather-sum its rows, single write of new_embedding_avg
__global__ __launch_bounds__(256) void gather_sum_kernel(
        const float* __restrict__ z, const float* __restrict__ emb,
        const int* __restrict__ sorted, const int* __restrict__ cursor,
        const int* __restrict__ counts, float* __restrict__ out) {
    int k = blockIdx.x * 4 + (threadIdx.x >> 6);
    int lane = threadIdx.x & 63;
    int cnt = counts[k];
    int start = cursor[k] - cnt;        // cursor was advanced by scatter
    float4 s = {0.f, 0.f, 0.f, 0.f};
    for (int i = 0; i < cnt; ++i) {
        int row = sorted[start + i];
        float4 v = *(const float4*)(z + (long)row * D + lane * 4);
        s.x += v.x; s.y += v.y; s.z += v.z; s.w += v.w;
    }
    float4 e = *(const float4*)(emb + (long)k * D + lane * 4);
    float4 o;
    o.x = e.x * DECAY + OMD * s.x;
    o.y = e.y * DECAY + OMD * s.y;
    o.z = e.z * DECAY + OMD * s.z;
    o.w = e.w * DECAY + OMD * s.w;
    *(float4*)(out + EMB_OFF + (long)k * D + lane * 4) = o;
}

__global__ __launch_bounds__(512) void quantize_kernel(
        const float* __restrict__ cb, const int* __restrict__ idxArr,
        float* __restrict__ out) {
    int tid = threadIdx.x;
    int r = tid >> 2, seg = tid & 3;
    int gRow = blockIdx.x * 128 + r;
    int code = idxArr[gRow];
    const float4* cbv = (const float4*)(cb + (long)code * D + seg * 64);
    float4* qv = (float4*)(out + Q_OFF + (long)gRow * D + seg * 64);
#pragma unroll 4
    for (int i = 0; i < 16; ++i) qv[i] = cbv[i];
}

__global__ void reduce_n(const float* __restrict__ out_cs, float* __restrict__ nacc) {
    int i = blockIdx.x * 256 + threadIdx.x;
    float v = out_cs[i];
    for (int off = 32; off; off >>= 1) v += __shfl_xor(v, off);
    __shared__ float wsum[4];
    int lane = threadIdx.x & 63, w = threadIdx.x >> 6;
    if (lane == 0) wsum[w] = v;
    __syncthreads();
    if (threadIdx.x == 0) atomicAdd(nacc, wsum[0] + wsum[1] + wsum[2] + wsum[3]);
}

__global__ void finalize_kernel(const float* __restrict__ nacc, float* __restrict__ out) {
    int k = blockIdx.x, d = threadIdx.x;
    float n = *nacc;
    float ncs = out[CS_OFF + k];
    float smoothed = (ncs + EPS) / (n + (float)K * EPS) * n;
    out[CB_OFF + (long)k * D + d] = out[EMB_OFF + (long)k * D + d] / smoothed;
}

extern "C" void kernel_launch(void* const* d_in, const int* in_sizes, int n_in,
                              void* d_out, int out_size, void* d_ws, size_t ws_size,
                              hipStream_t stream) {
    const float* z   = (const float*)d_in[0];
    const float* cb  = (const float*)d_in[1];
    const float* emb = (const float*)d_in[2];
    const float* cs  = (const float*)d_in[3];
    float* out = (float*)d_out;
    char* ws = (char*)d_ws;

    ulonglong2* tops = (ulonglong2*)(ws + WS_TOPS);
    unsigned long long* resolved = (unsigned long long*)(ws + WS_RES);
    int* idxArr = (int*)(ws + WS_IDX);
    float* c2 = (float*)(ws + WS_C2);
    int* flagRows = (int*)(ws + WS_FLAG);
    unsigned* flagCount = (unsigned*)(ws + WS_CNT);
    float* nacc = (float*)(ws + WS_CNT) + 1;
    int* counts = (int*)(ws + WS_CNTS);
    int* cursor = (int*)(ws + WS_CUR);
    int* sorted = (int*)(ws + WS_SORT);
    _Float16* cb16 = (_Float16*)(out + Q_OFF);   // scratch in quantized region

    init_kernel<<<N / 256, 256, 0, stream>>>(ws);
    cvt_cb16<<<K * D / 8 / 256, 256, 0, stream>>>(cb, cb16);
    c2_kernel<<<K, 64, 0, stream>>>(cb, c2);
    dim3 ggrid(N / BMt, KSPLIT);
    gemm_kernel<<<ggrid, GT, 0, stream>>>(z, cb16, c2, tops);
    merge_kernel<<<N / 256, 256, 0, stream>>>(tops, out, idxArr, flagCount, flagRows);
    dim3 rgrid(RSL, RKS);
    resolve_kernel<<<rgrid, 512, 0, stream>>>(z, cb, c2, flagCount, flagRows, resolved);
    writeback_kernel<<<N / 256, 256, 0, stream>>>(flagCount, flagRows, resolved, idxArr, out);
    count_kernel<<<N / 256, 256, 0, stream>>>(idxArr, counts);
    scan_kernel<<<1, 1024, 0, stream>>>(counts, cs, cursor, out);
    scatter_kernel<<<N / 256, 256, 0, stream>>>(idxArr, cursor, sorted);
    gather_sum_kernel<<<K / 4, 256, 0, stream>>>(z, emb, sorted, cursor, counts, out);
    reduce_n<<<K / 256, 256, 0, stream>>>(out + CS_OFF, nacc);
    finalize_kernel<<<K, 256, 0, stream>>>(nacc, out);
    quantize_kernel<<<N / 128, 512, 0, stream>>>(cb, idxArr, out);
}

// Round 9
// 639.673 us; speedup vs baseline: 4.8806x; 1.0060x over previous
//
#include <hip/hip_runtime.h>

// EMA codebook update (VQ-VAE), MI355X. fp16-MFMA distance filter + exact
// fp32 rescore for near-ties. N=32768, K=8192, D=256.
// R9: gemm at 1024 threads / 16 waves (4 waves/SIMD, wave tile 64x32) for
//     occupancy; tail fused: prep(init+cvt+c2), counts in merge/writeback,
//     n computed in scan. 10 launches (was 14).

#define DECAY 0.99f
#define OMD 0.01f
#define EPS 1e-5f
#define DELTA 0.3f

constexpr int N = 32768, K = 8192, D = 256;
constexpr int KSPLIT = 2;               // gemm grid: 128 row-tiles x 2 code-splits
constexpr int BMt = 256, BNt = 128;     // gemm tile
constexpr int GT = 1024;                // gemm threads (16 waves: 4M x 4N)

// resolve config (R2-style tile)
constexpr int RBM = 128;                // flagged rows per group
constexpr int RBN = 128;                // code tile per kb step
constexpr int RKS = 32;                 // K splits (256 codes each)
constexpr int RSL = 32;                 // group slots
constexpr int RDC = 32;                 // d-chunk

typedef _Float16 f16x8 __attribute__((ext_vector_type(8)));
typedef float f32x4 __attribute__((ext_vector_type(4)));

// d_out layout (floats, reference return order)
constexpr long Q_OFF   = 0;
constexpr long IDX_OFF = (long)N * D;
constexpr long CB_OFF  = IDX_OFF + N;
constexpr long EMB_OFF = CB_OFF + (long)K * D;
constexpr long CS_OFF  = EMB_OFF + (long)K * D;

// ws layout (bytes)
constexpr long WS_TOPS = 0;                          // ulonglong2[N*KSPLIT]
constexpr long WS_RES  = WS_TOPS + (long)N * 2 * 16; // u64[N] resolved
constexpr long WS_IDX  = WS_RES + (long)N * 8;       // int[N]
constexpr long WS_C2   = WS_IDX + (long)N * 4;       // float[K]
constexpr long WS_FLAG = WS_C2 + (long)K * 4;        // int[N] flagged rows
constexpr long WS_CNT  = WS_FLAG + (long)N * 4;      // [0] u32 count, [1] f32 nacc
constexpr long WS_CNTS = WS_CNT + 8;                 // int[K] histogram
constexpr long WS_CUR  = WS_CNTS + (long)K * 4;      // int[K] scan/cursor
constexpr long WS_SORT = WS_CUR + (long)K * 4;       // int[N] rows sorted by code

#define GLOAD_LDS16(g, l) __builtin_amdgcn_global_load_lds(                    \
    (const __attribute__((address_space(1))) void*)(g),                        \
    (__attribute__((address_space(3))) void*)(l), 16, 0, 0)

__device__ inline unsigned transScore(float s) {
    unsigned u = __float_as_uint(s);
    return u ^ ((unsigned)((int)u >> 31) | 0x80000000u);   // order-preserving
}
__device__ inline float untransScore(unsigned u) {
    return (u & 0x80000000u) ? __uint_as_float(u ^ 0x80000000u)
                             : __uint_as_float(~u);
}

// prep: c2 + fp32->fp16 codebook + all workspace init. grid K x 64.
__global__ void prep_kernel(const float* __restrict__ cb, _Float16* __restrict__ cb16,
                            float* __restrict__ c2, char* __restrict__ ws) {
    int k = blockIdx.x, lane = threadIdx.x;
    float4 v = ((const float4*)(cb + (long)k * D))[lane];
    float s = v.x * v.x + v.y * v.y + v.z * v.z + v.w * v.w;
    for (int off = 32; off; off >>= 1) s += __shfl_xor(s, off);
    if (lane == 0) c2[k] = s;
    union { _Float16 h[4]; unsigned long long u; } t;
    t.h[0] = (_Float16)v.x; t.h[1] = (_Float16)v.y;
    t.h[2] = (_Float16)v.z; t.h[3] = (_Float16)v.w;
    *(unsigned long long*)(cb16 + (long)k * D + lane * 4) = t.u;
    if (k < N / 64) ((unsigned long long*)(ws + WS_RES))[k * 64 + lane] = ~0ull;
    if (lane == 0) ((int*)(ws + WS_CNTS))[k] = 0;
    if (k == 0 && lane == 0) ((unsigned*)(ws + WS_CNT))[0] = 0u;
}

// ---------------- fp16 MFMA distance GEMM with top-2 tracking ----------------
__global__ __launch_bounds__(GT, 4) void gemm_kernel(
        const float* __restrict__ z, const _Float16* __restrict__ cb16,
        const float* __restrict__ c2, ulonglong2* __restrict__ tops) {
    __shared__ _Float16 As[BMt * 256];          // 128 KB, swizzled
    __shared__ _Float16 Bs[2][BNt * 32];        // 2 x 8 KB, swizzled
    __shared__ unsigned long long L1[BMt];      // block-level top1 (score|idx)
    __shared__ unsigned L2s[BMt];               // block-level top2 score

    const int tid = threadIdx.x;
    const int lane = tid & 63;
    const int wave = tid >> 6;                  // 16 waves: 4(M) x 4(N)
    const int wm = wave >> 2, wn = wave & 3;
    const long rowBase = (long)blockIdx.x * BMt;
    const int kbase = blockIdx.y * (K / KSPLIT);

    // ---- stage A (z rows) once: fp32 -> fp16, swizzled (validated layout) ----
    for (int i = 0; i < 8; ++i) {
        int id = tid + i * GT;                  // 8192 chunks of 8 floats
        int r = id >> 5, dseg = (id & 31) * 8;
        const float4* src = (const float4*)(z + (rowBase + r) * D + dseg);
        float4 v0 = src[0], v1 = src[1];
        union { _Float16 h[8]; ulonglong2 u; } t;
        t.h[0] = (_Float16)v0.x; t.h[1] = (_Float16)v0.y;
        t.h[2] = (_Float16)v0.z; t.h[3] = (_Float16)v0.w;
        t.h[4] = (_Float16)v1.x; t.h[5] = (_Float16)v1.y;
        t.h[6] = (_Float16)v1.z; t.h[7] = (_Float16)v1.w;
        int byte = (r * 256 + dseg) * 2;
        byte ^= (r & 7) << 4;
        *(ulonglong2*)((char*)As + byte) = t.u;
    }

    // ---- per-thread B-staging slot (tid<512): inverse of LDS read swizzle ----
    const bool bstage = tid < 512;
    int bc = 0, bt = 0;
    if (bstage) {
        int h = tid >> 3, rr = tid & 7;
        bc = 2 * h; bt = rr ^ (bc & 7);
        if (bt & 4) { bc++; bt = (rr ^ (bc & 7)) & 3; }
    }
    char* ldsB0 = (char*)&Bs[0][0] + tid * 16;
    char* ldsB1 = (char*)&Bs[1][0] + tid * 16;

    if (bstage)                                  // B chunk 0 (kb=0, dcI=0)
        GLOAD_LDS16(cb16 + ((long)(kbase + bc) << 8) + bt * 8, ldsB0);

    if (tid < BMt) { L1[tid] = ~0ull; L2s[tid] = 0xFFFFFFFFu; }
    __syncthreads();                            // drains vmcnt + LDS writes

    // per-thread A/B frag byte offsets. A: xor applied AFTER adding dc.
    int aBase[4], aSwz[4], bOff[2];
#pragma unroll
    for (int fr = 0; fr < 4; ++fr) {
        int r = wm * 64 + fr * 16 + (lane & 15);
        aBase[fr] = r * 512 + (lane >> 4) * 16;
        aSwz[fr] = (r & 7) << 4;
    }
#pragma unroll
    for (int fc = 0; fc < 2; ++fc) {
        int c = wn * 32 + fc * 16 + (lane & 15);
        int byte = c * 64 + (lane >> 4) * 16;
        bOff[fc] = byte ^ ((c & 7) << 4);
    }

    f32x4 acc[4][2];
    float bV[16], bT2[16];
    int bI[16];
#pragma unroll
    for (int s = 0; s < 16; ++s) { bV[s] = 3.4e38f; bT2[s] = 3.4e38f; bI[s] = 0; }
    float c2v[2];

    const int NCH = (K / KSPLIT / BNt) * 8;      // 256 chunks
    int cur = 0;
    for (int j = 0; j < NCH; ++j) {
        const int kb = j >> 3, dcI = j & 7, dc = dcI * 32;
        // stage next chunk direct-to-LDS
        if (bstage && j + 1 < NCH) {
            int jj = j + 1;
            const _Float16* src = cb16
                + ((long)(kbase + (jj >> 3) * BNt + bc) << 8)
                + (jj & 7) * 32 + bt * 8;
            GLOAD_LDS16(src, cur ? ldsB0 : ldsB1);
        }
        if (dcI == 0) {
#pragma unroll
            for (int a = 0; a < 4; ++a)
#pragma unroll
                for (int b = 0; b < 2; ++b) acc[a][b] = (f32x4)0.f;
#pragma unroll
            for (int fc = 0; fc < 2; ++fc)
                c2v[fc] = c2[kbase + kb * BNt + wn * 32 + fc * 16 + (lane & 15)];
        }
        f16x8 aF[4], bF[2];
#pragma unroll
        for (int fr = 0; fr < 4; ++fr)
            aF[fr] = *(const f16x8*)((const char*)As +
                        ((aBase[fr] + dc * 2) ^ aSwz[fr]));
#pragma unroll
        for (int fc = 0; fc < 2; ++fc)
            bF[fc] = *(const f16x8*)((const char*)&Bs[cur][0] + bOff[fc]);
#pragma unroll
        for (int fr = 0; fr < 4; ++fr)
#pragma unroll
            for (int fc = 0; fc < 2; ++fc)
                acc[fr][fc] = __builtin_amdgcn_mfma_f32_16x16x32_f16(
                    aF[fr], bF[fc], acc[fr][fc], 0, 0, 0);
        if (dcI == 7) {
            // score + float top-2 (ties covered by DELTA rescore)
#pragma unroll
            for (int fc = 0; fc < 2; ++fc) {
                int gcol = kbase + kb * BNt + wn * 32 + fc * 16 + (lane & 15);
#pragma unroll
                for (int fr = 0; fr < 4; ++fr)
#pragma unroll
                    for (int r = 0; r < 4; ++r) {
                        float s = fmaf(-2.f, acc[fr][fc][r], c2v[fc]);
                        int slot = fr * 4 + r;
                        float t1o = bV[slot];
                        bT2[slot] = fminf(bT2[slot], fmaxf(s, t1o));
                        bool lt = s < t1o;
                        bV[slot] = lt ? s : t1o;
                        bI[slot] = lt ? gcol : bI[slot];
                    }
            }
        }
        __syncthreads();             // drain stage loads; guard Bs reuse
        cur ^= 1;
    }

    // intra-wave top2 merge over the 16 lanes sharing each row (float domain)
#pragma unroll
    for (int m = 1; m < 16; m <<= 1) {
#pragma unroll
        for (int s = 0; s < 16; ++s) {
            float ov = __shfl_xor(bV[s], m);
            int   oi = __shfl_xor(bI[s], m);
            float o2 = __shfl_xor(bT2[s], m);
            float nt2 = fminf(fminf(bT2[s], o2), fmaxf(bV[s], ov));
            bool take = ov < bV[s];
            bV[s] = take ? ov : bV[s];
            bI[s] = take ? oi : bI[s];
            bT2[s] = nt2;
        }
    }
    // cross-wave (4 wn waves) top2 merge via LDS atomicMin-displacement
    if ((lane & 15) == 0) {
#pragma unroll
        for (int s = 0; s < 16; ++s) {
            int row = wm * 64 + (s >> 2) * 16 + (lane >> 4) * 4 + (s & 3);
            unsigned long long t1 =
                ((unsigned long long)transScore(bV[s]) << 32) | (unsigned)bI[s];
            unsigned long long old1 = atomicMin(&L1[row], t1);
            unsigned long long cand = t1 < old1 ? old1 : t1;
            atomicMin(&L2s[row], (unsigned)(cand >> 32));
            atomicMin(&L2s[row], transScore(bT2[s]));
        }
    }
    __syncthreads();
    if (tid < BMt) {
        ulonglong2 v; v.x = L1[tid]; v.y = (unsigned long long)L2s[tid];
        tops[(rowBase + tid) * KSPLIT + blockIdx.y] = v;
    }
}

// merge + histogram of confidently-resolved rows
__global__ void merge_kernel(const ulonglong2* __restrict__ tops,
                             float* __restrict__ out, int* __restrict__ idxArr,
                             unsigned* __restrict__ flagCount,
                             int* __restrict__ flagRows, int* __restrict__ counts) {
    int row = blockIdx.x * 256 + threadIdx.x;
    ulonglong2 a = tops[row * 2], b = tops[row * 2 + 1];
    unsigned long long t1 = a.x < b.x ? a.x : b.x;
    unsigned a1 = (unsigned)(a.x >> 32), b1 = (unsigned)(b.x >> 32);
    unsigned mx = a1 > b1 ? a1 : b1;
    unsigned t2 = (unsigned)a.y < (unsigned)b.y ? (unsigned)a.y : (unsigned)b.y;
    t2 = t2 < mx ? t2 : mx;
    float s1 = untransScore((unsigned)(t1 >> 32));
    float s2 = untransScore(t2);
    int idx = (int)(t1 & 0xFFFFFFFFull);
    idxArr[row] = idx;
    out[IDX_OFF + row] = (float)idx;
    if (s2 - s1 <= DELTA) {
        unsigned p = atomicAdd(flagCount, 1u);
        flagRows[p] = row;
    } else {
        atomicAdd(&counts[idx], 1);
    }
}

// exact fp32 rescore of flagged rows. Grid = (RSL group slots, RKS K-splits).
__global__ __launch_bounds__(512) void resolve_kernel(
        const float* __restrict__ z, const float* __restrict__ cb,
        const float* __restrict__ c2, const unsigned* __restrict__ flagCount,
        const int* __restrict__ flagRows, unsigned long long* __restrict__ resolved) {
    __shared__ float zT[RDC][RBM + 4];
    __shared__ float cT[RDC][RBN + 4];
    __shared__ float c2s[RBN];
    __shared__ int rid[RBM];

    const int cnt = (int)*flagCount;
    const int tid = threadIdx.x;
    const int tx = tid & 31, ty = tid >> 5;
    const int rbase = ty * 8, cbase = tx * 4;
    const int k0 = blockIdx.y * (K / RKS);          // 256 codes per split

    for (int g = blockIdx.x; g * RBM < cnt; g += RSL) {
        __syncthreads();                // previous iteration fully done
        if (tid < RBM) {
            int fi = g * RBM + tid;
            rid[tid] = flagRows[fi < cnt ? fi : cnt - 1];   // pad = dup row (harmless)
        }

        float bestV[8]; int bestI[8];
#pragma unroll
        for (int r = 0; r < 8; ++r) { bestV[r] = 3.4e38f; bestI[r] = 0; }

        for (int kb = k0; kb < k0 + K / RKS; kb += RBN) {   // 2 iterations
            __syncthreads();            // prior score-phase reads of c2s done
            if (tid < RBN) c2s[tid] = c2[kb + tid];

            float acc[8][4];
#pragma unroll
            for (int r = 0; r < 8; ++r)
#pragma unroll
                for (int c = 0; c < 4; ++c) acc[r][c] = 0.f;

            for (int dc = 0; dc < D; dc += RDC) {
                __syncthreads();        // prior compute reads of zT/cT done
#pragma unroll
                for (int s = 0; s < 2; ++s) {
                    int f = tid + s * 512;          // 1024 float4 slots
                    int row = f >> 3, dq = f & 7;
                    float4 v = *(const float4*)(z + (long)rid[row] * D + dc + dq * 4);
                    zT[dq * 4 + 0][row] = v.x; zT[dq * 4 + 1][row] = v.y;
                    zT[dq * 4 + 2][row] = v.z; zT[dq * 4 + 3][row] = v.w;
                    float4 w = *(const float4*)(cb + (long)(kb + row) * D + dc + dq * 4);
                    cT[dq * 4 + 0][row] = w.x; cT[dq * 4 + 1][row] = w.y;
                    cT[dq * 4 + 2][row] = w.z; cT[dq * 4 + 3][row] = w.w;
                }
                __syncthreads();
#pragma unroll
                for (int d = 0; d < RDC; ++d) {
                    float a[8], b[4];
                    *(float4*)&a[0] = *(const float4*)&zT[d][rbase];
                    *(float4*)&a[4] = *(const float4*)&zT[d][rbase + 4];
                    *(float4*)&b[0] = *(const float4*)&cT[d][cbase];
#pragma unroll
                    for (int r = 0; r < 8; ++r)
#pragma unroll
                        for (int c = 0; c < 4; ++c)
                            acc[r][c] = fmaf(a[r], b[c], acc[r][c]);
                }
            }
            // score phase: c2 - 2*zc (z2 row-constant, argmin-invariant)
#pragma unroll
            for (int c = 0; c < 4; ++c) {
                float cc = c2s[cbase + c];
                int col = kb + cbase + c;
#pragma unroll
                for (int r = 0; r < 8; ++r) {
                    float score = fmaf(-2.f, acc[r][c], cc);
                    if (score < bestV[r]) { bestV[r] = score; bestI[r] = col; }
                }
            }
        }
        // reduce across the 32 tx-lanes sharing rows; first-index ties
#pragma unroll
        for (int off = 16; off; off >>= 1) {
#pragma unroll
            for (int r = 0; r < 8; ++r) {
                float ov = __shfl_xor(bestV[r], off);
                int   oi = __shfl_xor(bestI[r], off);
                if (ov < bestV[r] || (ov == bestV[r] && oi < bestI[r])) {
                    bestV[r] = ov; bestI[r] = oi;
                }
            }
        }
        if (tx == 0) {
#pragma unroll
            for (int r = 0; r < 8; ++r) {
                unsigned long long u =
                    ((unsigned long long)transScore(bestV[r]) << 32)
                    | (unsigned)bestI[r];
                atomicMin(&resolved[rid[rbase + r]], u);
            }
        }
    }
}

// writeback + histogram of flagged rows
__global__ void writeback_kernel(const unsigned* __restrict__ flagCount,
                                 const int* __restrict__ flagRows,
                                 const unsigned long long* __restrict__ resolved,
                                 int* __restrict__ idxArr, float* __restrict__ out,
                                 int* __restrict__ counts) {
    int i = blockIdx.x * 256 + threadIdx.x;
    if (i < (int)*flagCount) {
        int row = flagRows[i];
        int idx = (int)(resolved[row] & 0xFFFFFFFFull);
        idxArr[row] = idx;
        out[IDX_OFF + row] = (float)idx;
        atomicAdd(&counts[idx], 1);
    }
}

// single block: exclusive scan of counts -> cursor, CS output, n scalar
__global__ __launch_bounds__(1024) void scan_kernel(
        const int* __restrict__ counts, const float* __restrict__ cs,
        int* __restrict__ cursor, float* __restrict__ out,
        float* __restrict__ nacc) {
    __shared__ int s[1024];
    __shared__ float csred[16];
    int tid = threadIdx.x;
    int base = tid * 8;                 // 8192 / 1024
    int4 c0 = ((const int4*)(counts + base))[0];
    int4 c1 = ((const int4*)(counts + base))[1];
    float4 f0 = ((const float4*)(cs + base))[0];
    float4 f1 = ((const float4*)(cs + base))[1];
    int local[8] = {c0.x, c0.y, c0.z, c0.w, c1.x, c1.y, c1.z, c1.w};
    float csv[8] = {f0.x, f0.y, f0.z, f0.w, f1.x, f1.y, f1.z, f1.w};
    int sum = 0; float csum = 0.f;
#pragma unroll
    for (int i = 0; i < 8; ++i) { sum += local[i]; csum += csv[i]; }
    s[tid] = sum;
    __syncthreads();
    for (int off = 1; off < 1024; off <<= 1) {
        int v = (tid >= off) ? s[tid - off] : 0;
        __syncthreads();
        s[tid] += v;
        __syncthreads();
    }
    int run = s[tid] - sum;             // exclusive prefix of this chunk
#pragma unroll
    for (int i = 0; i < 8; ++i) {
        cursor[base + i] = run;
        out[CS_OFF + base + i] = csv[i] * DECAY + OMD * (float)local[i];
        run += local[i];
    }
    // n = DECAY * sum(cs) + OMD * N  (sum(counts) == N exactly)
    for (int off = 32; off; off >>= 1) csum += __shfl_xor(csum, off);
    if ((tid & 63) == 0) csred[tid >> 6] = csum;
    __syncthreads();
    if (tid == 0) {
        float t = 0.f;
#pragma unroll
        for (int i = 0; i < 16; ++i) t += csred[i];
        *nacc = t * DECAY + OMD * (float)N;
    }
}

__global__ void scatter_kernel(const int* __restrict__ idxArr,
                               int* __restrict__ cursor, int* __restrict__ sorted) {
    int row = blockIdx.x * 256 + threadIdx.x;
    int pos = atomicAdd(&cursor[idxArr[row]], 1);
    sorted[pos] = row;
}

// one wave per code: gather-sum its rows, single write of new_embedding_avg
__global__ __launch_bounds__(256) void gather_sum_kernel(
        const float* __restrict__ z, const float* __restrict__ emb,
        const int* __restrict__ sorted, const int* __restrict__ cursor,
        const int* __restrict__ counts, float* __restrict__ out) {
    int k = blockIdx.x * 4 + (threadIdx.x >> 6);
    int lane = threadIdx.x & 63;
    int cnt = counts[k];
    int start = cursor[k] - cnt;        // cursor was advanced by scatter
    float4 s = {0.f, 0.f, 0.f, 0.f};
    for (int i = 0; i < cnt; ++i) {
        int row = sorted[start + i];
        float4 v = *(const float4*)(z + (long)row * D + lane * 4);
        s.x += v.x; s.y += v.y; s.z += v.z; s.w += v.w;
    }
    float4 e = *(const float4*)(emb + (long)k * D + lane * 4);
    float4 o;
    o.x = e.x * DECAY + OMD * s.x;
    o.y = e.y * DECAY + OMD * s.y;
    o.z = e.z * DECAY + OMD * s.z;
    o.w = e.w * DECAY + OMD * s.w;
    *(float4*)(out + EMB_OFF + (long)k * D + lane * 4) = o;
}

__global__ __launch_bounds__(512) void quantize_kernel(
        const float* __restrict__ cb, const int* __restrict__ idxArr,
        float* __restrict__ out) {
    int tid = threadIdx.x;
    int r = tid >> 2, seg = tid & 3;
    int gRow = blockIdx.x * 128 + r;
    int code = idxArr[gRow];
    const float4* cbv = (const float4*)(cb + (long)code * D + seg * 64);
    float4* qv = (float4*)(out + Q_OFF + (long)gRow * D + seg * 64);
#pragma unroll 4
    for (int i = 0; i < 16; ++i) qv[i] = cbv[i];
}

__global__ void finalize_kernel(const float* __restrict__ nacc, float* __restrict__ out) {
    int k = blockIdx.x, d = threadIdx.x;
    float n = *nacc;
    float ncs = out[CS_OFF + k];
    float smoothed = (ncs + EPS) / (n + (float)K * EPS) * n;
    out[CB_OFF + (long)k * D + d] = out[EMB_OFF + (long)k * D + d] / smoothed;
}

extern "C" void kernel_launch(void* const* d_in, const int* in_sizes, int n_in,
                              void* d_out, int out_size, void* d_ws, size_t ws_size,
                              hipStream_t stream) {
    const float* z   = (const float*)d_in[0];
    const float* cb  = (const float*)d_in[1];
    const float* emb = (const float*)d_in[2];
    const float* cs  = (const float*)d_in[3];
    float* out = (float*)d_out;
    char* ws = (char*)d_ws;

    ulonglong2* tops = (ulonglong2*)(ws + WS_TOPS);
    unsigned long long* resolved = (unsigned long long*)(ws + WS_RES);
    int* idxArr = (int*)(ws + WS_IDX);
    float* c2 = (float*)(ws + WS_C2);
    int* flagRows = (int*)(ws + WS_FLAG);
    unsigned* flagCount = (unsigned*)(ws + WS_CNT);
    float* nacc = (float*)(ws + WS_CNT) + 1;
    int* counts = (int*)(ws + WS_CNTS);
    int* cursor = (int*)(ws + WS_CUR);
    int* sorted = (int*)(ws + WS_SORT);
    _Float16* cb16 = (_Float16*)(out + Q_OFF);   // scratch in quantized region

    prep_kernel<<<K, 64, 0, stream>>>(cb, cb16, c2, ws);
    dim3 ggrid(N / BMt, KSPLIT);
    gemm_kernel<<<ggrid, GT, 0, stream>>>(z, cb16, c2, tops);
    merge_kernel<<<N / 256, 256, 0, stream>>>(tops, out, idxArr, flagCount,
                                              flagRows, counts);
    dim3 rgrid(RSL, RKS);
    resolve_kernel<<<rgrid, 512, 0, stream>>>(z, cb, c2, flagCount, flagRows, resolved);
    writeback_kernel<<<N / 256, 256, 0, stream>>>(flagCount, flagRows, resolved,
                                                  idxArr, out, counts);
    scan_kernel<<<1, 1024, 0, stream>>>(counts, cs, cursor, out, nacc);
    scatter_kernel<<<N / 256, 256, 0, stream>>>(idxArr, cursor, sorted);
    gather_sum_kernel<<<K / 4, 256, 0, stream>>>(z, emb, sorted, cursor, counts, out);
    finalize_kernel<<<K, 256, 0, stream>>>(nacc, out);
    quantize_kernel<<<N / 128, 512, 0, stream>>>(cb, idxArr, out);
}

// Round 10
// 611.505 us; speedup vs baseline: 5.1054x; 1.0461x over previous
//
#include <hip/hip_runtime.h>

// EMA codebook update (VQ-VAE), MI355X. fp16-MFMA distance filter + exact
// fp32 rescore for near-ties. N=32768, K=8192, D=256.
// R10: gemm BM=128 / LDS 80KiB exactly -> 2 blocks/CU (cross-block overlap
//      of barrier stalls); top2-merge arrays unioned into Bs after K-loop;
//      finalize folded into gather_sum; shfl scan. 9 launches.

#define DECAY 0.99f
#define OMD 0.01f
#define EPS 1e-5f
#define DELTA 0.3f

constexpr int N = 32768, K = 8192, D = 256;
constexpr int KSPLIT = 2;               // gemm grid: 256 row-tiles x 2 code-splits
constexpr int BMt = 128, BNt = 128;     // gemm tile
constexpr int GT = 512;                 // gemm threads (8 waves: 2M x 4N)

// resolve config (R2-style tile)
constexpr int RBM = 128;                // flagged rows per group
constexpr int RBN = 128;                // code tile per kb step
constexpr int RKS = 32;                 // K splits (256 codes each)
constexpr int RSL = 32;                 // group slots
constexpr int RDC = 32;                 // d-chunk

typedef _Float16 f16x8 __attribute__((ext_vector_type(8)));
typedef float f32x4 __attribute__((ext_vector_type(4)));

// d_out layout (floats, reference return order)
constexpr long Q_OFF   = 0;
constexpr long IDX_OFF = (long)N * D;
constexpr long CB_OFF  = IDX_OFF + N;
constexpr long EMB_OFF = CB_OFF + (long)K * D;
constexpr long CS_OFF  = EMB_OFF + (long)K * D;

// ws layout (bytes)
constexpr long WS_TOPS = 0;                          // ulonglong2[N*KSPLIT]
constexpr long WS_RES  = WS_TOPS + (long)N * 2 * 16; // u64[N] resolved
constexpr long WS_IDX  = WS_RES + (long)N * 8;       // int[N]
constexpr long WS_C2   = WS_IDX + (long)N * 4;       // float[K]
constexpr long WS_FLAG = WS_C2 + (long)K * 4;        // int[N] flagged rows
constexpr long WS_CNT  = WS_FLAG + (long)N * 4;      // [0] u32 count, [1] f32 nacc
constexpr long WS_CNTS = WS_CNT + 8;                 // int[K] histogram
constexpr long WS_CUR  = WS_CNTS + (long)K * 4;      // int[K] scan/cursor
constexpr long WS_SORT = WS_CUR + (long)K * 4;       // int[N] rows sorted by code

#define GLOAD_LDS16(g, l) __builtin_amdgcn_global_load_lds(                    \
    (const __attribute__((address_space(1))) void*)(g),                        \
    (__attribute__((address_space(3))) void*)(l), 16, 0, 0)

__device__ inline unsigned transScore(float s) {
    unsigned u = __float_as_uint(s);
    return u ^ ((unsigned)((int)u >> 31) | 0x80000000u);   // order-preserving
}
__device__ inline float untransScore(unsigned u) {
    return (u & 0x80000000u) ? __uint_as_float(u ^ 0x80000000u)
                             : __uint_as_float(~u);
}

// prep: c2 + fp32->fp16 codebook + all workspace init. grid K x 64.
__global__ void prep_kernel(const float* __restrict__ cb, _Float16* __restrict__ cb16,
                            float* __restrict__ c2, char* __restrict__ ws) {
    int k = blockIdx.x, lane = threadIdx.x;
    float4 v = ((const float4*)(cb + (long)k * D))[lane];
    float s = v.x * v.x + v.y * v.y + v.z * v.z + v.w * v.w;
    for (int off = 32; off; off >>= 1) s += __shfl_xor(s, off);
    if (lane == 0) c2[k] = s;
    union { _Float16 h[4]; unsigned long long u; } t;
    t.h[0] = (_Float16)v.x; t.h[1] = (_Float16)v.y;
    t.h[2] = (_Float16)v.z; t.h[3] = (_Float16)v.w;
    *(unsigned long long*)(cb16 + (long)k * D + lane * 4) = t.u;
    if (k < N / 64) ((unsigned long long*)(ws + WS_RES))[k * 64 + lane] = ~0ull;
    if (lane == 0) ((int*)(ws + WS_CNTS))[k] = 0;
    if (k == 0 && lane == 0) ((unsigned*)(ws + WS_CNT))[0] = 0u;
}

// ---------------- fp16 MFMA distance GEMM with top-2 tracking ----------------
__global__ __launch_bounds__(GT, 4) void gemm_kernel(
        const float* __restrict__ z, const _Float16* __restrict__ cb16,
        const float* __restrict__ c2, ulonglong2* __restrict__ tops) {
    __shared__ _Float16 As[BMt * 256];          // 64 KB, swizzled
    __shared__ _Float16 Bs[2][BNt * 32];        // 2 x 8 KB, swizzled
    // total 81920 B exactly -> 2 blocks/CU. Top2 merge arrays live in Bs
    // space after the K-loop (union).

    const int tid = threadIdx.x;
    const int lane = tid & 63;
    const int wave = tid >> 6;                  // 8 waves: 2(M) x 4(N)
    const int wm = wave >> 2, wn = wave & 3;
    const long rowBase = (long)blockIdx.x * BMt;
    const int kbase = blockIdx.y * (K / KSPLIT);

    // ---- stage A (z rows) once: fp32 -> fp16, swizzled (validated layout) ----
    for (int i = 0; i < 8; ++i) {
        int id = tid + i * GT;                  // 4096 chunks of 8 floats
        int r = id >> 5, dseg = (id & 31) * 8;
        const float4* src = (const float4*)(z + (rowBase + r) * D + dseg);
        float4 v0 = src[0], v1 = src[1];
        union { _Float16 h[8]; ulonglong2 u; } t;
        t.h[0] = (_Float16)v0.x; t.h[1] = (_Float16)v0.y;
        t.h[2] = (_Float16)v0.z; t.h[3] = (_Float16)v0.w;
        t.h[4] = (_Float16)v1.x; t.h[5] = (_Float16)v1.y;
        t.h[6] = (_Float16)v1.z; t.h[7] = (_Float16)v1.w;
        int byte = (r * 256 + dseg) * 2;
        byte ^= (r & 7) << 4;
        *(ulonglong2*)((char*)As + byte) = t.u;
    }

    // ---- per-thread B-staging slot: inverse of the LDS read swizzle ----
    int bc, bt;
    {
        int h = tid >> 3, rr = tid & 7;
        bc = 2 * h; bt = rr ^ (bc & 7);
        if (bt & 4) { bc++; bt = (rr ^ (bc & 7)) & 3; }
    }
    char* ldsB0 = (char*)&Bs[0][0] + tid * 16;
    char* ldsB1 = (char*)&Bs[1][0] + tid * 16;

    // B chunk 0 (kb=0, dcI=0)
    GLOAD_LDS16(cb16 + ((long)(kbase + bc) << 8) + bt * 8, ldsB0);
    __syncthreads();                            // drains vmcnt + LDS writes

    // per-thread A/B frag byte offsets. A: xor applied AFTER adding dc.
    int aBase[4], aSwz[4], bOff[2];
#pragma unroll
    for (int fr = 0; fr < 4; ++fr) {
        int r = wm * 64 + fr * 16 + (lane & 15);
        aBase[fr] = r * 512 + (lane >> 4) * 16;
        aSwz[fr] = (r & 7) << 4;
    }
#pragma unroll
    for (int fc = 0; fc < 2; ++fc) {
        int c = wn * 32 + fc * 16 + (lane & 15);
        int byte = c * 64 + (lane >> 4) * 16;
        bOff[fc] = byte ^ ((c & 7) << 4);
    }

    f32x4 acc[4][2];
    float bV[16], bT2[16];
    int bI[16];
#pragma unroll
    for (int s = 0; s < 16; ++s) { bV[s] = 3.4e38f; bT2[s] = 3.4e38f; bI[s] = 0; }
    float c2v[2];

    const int NCH = (K / KSPLIT / BNt) * 8;      // 256 chunks
    int cur = 0;
    for (int j = 0; j < NCH; ++j) {
        const int kb = j >> 3, dcI = j & 7, dc = dcI * 32;
        // stage next chunk direct-to-LDS
        if (j + 1 < NCH) {
            int jj = j + 1;
            const _Float16* src = cb16
                + ((long)(kbase + (jj >> 3) * BNt + bc) << 8)
                + (jj & 7) * 32 + bt * 8;
            GLOAD_LDS16(src, cur ? ldsB0 : ldsB1);
        }
        if (dcI == 0) {
#pragma unroll
            for (int a = 0; a < 4; ++a)
#pragma unroll
                for (int b = 0; b < 2; ++b) acc[a][b] = (f32x4)0.f;
#pragma unroll
            for (int fc = 0; fc < 2; ++fc)
                c2v[fc] = c2[kbase + kb * BNt + wn * 32 + fc * 16 + (lane & 15)];
        }
        f16x8 aF[4], bF[2];
#pragma unroll
        for (int fr = 0; fr < 4; ++fr)
            aF[fr] = *(const f16x8*)((const char*)As +
                        ((aBase[fr] + dc * 2) ^ aSwz[fr]));
#pragma unroll
        for (int fc = 0; fc < 2; ++fc)
            bF[fc] = *(const f16x8*)((const char*)&Bs[cur][0] + bOff[fc]);
#pragma unroll
        for (int fr = 0; fr < 4; ++fr)
#pragma unroll
            for (int fc = 0; fc < 2; ++fc)
                acc[fr][fc] = __builtin_amdgcn_mfma_f32_16x16x32_f16(
                    aF[fr], bF[fc], acc[fr][fc], 0, 0, 0);
        if (dcI == 7) {
            // score + float top-2 (ties covered by DELTA rescore)
#pragma unroll
            for (int fc = 0; fc < 2; ++fc) {
                int gcol = kbase + kb * BNt + wn * 32 + fc * 16 + (lane & 15);
#pragma unroll
                for (int fr = 0; fr < 4; ++fr)
#pragma unroll
                    for (int r = 0; r < 4; ++r) {
                        float s = fmaf(-2.f, acc[fr][fc][r], c2v[fc]);
                        int slot = fr * 4 + r;
                        float t1o = bV[slot];
                        bT2[slot] = fminf(bT2[slot], fmaxf(s, t1o));
                        bool lt = s < t1o;
                        bV[slot] = lt ? s : t1o;
                        bI[slot] = lt ? gcol : bI[slot];
                    }
            }
        }
        __syncthreads();             // drain stage loads; guard Bs reuse
        cur ^= 1;
    }

    // intra-wave top2 merge over the 16 lanes sharing each row (float domain)
#pragma unroll
    for (int m = 1; m < 16; m <<= 1) {
#pragma unroll
        for (int s = 0; s < 16; ++s) {
            float ov = __shfl_xor(bV[s], m);
            int   oi = __shfl_xor(bI[s], m);
            float o2 = __shfl_xor(bT2[s], m);
            float nt2 = fminf(fminf(bT2[s], o2), fmaxf(bV[s], ov));
            bool take = ov < bV[s];
            bV[s] = take ? ov : bV[s];
            bI[s] = take ? oi : bI[s];
            bT2[s] = nt2;
        }
    }
    // cross-wave (4 wn waves) top2 merge via LDS atomicMin-displacement,
    // arrays unioned into Bs (K-loop done, last barrier passed).
    unsigned long long* L1 = (unsigned long long*)&Bs[0][0];   // 1 KB
    unsigned* L2s = (unsigned*)(L1 + BMt);                     // 512 B
    if (tid < BMt) { L1[tid] = ~0ull; L2s[tid] = 0xFFFFFFFFu; }
    __syncthreads();
    if ((lane & 15) == 0) {
#pragma unroll
        for (int s = 0; s < 16; ++s) {
            int row = wm * 64 + (s >> 2) * 16 + (lane >> 4) * 4 + (s & 3);
            unsigned long long t1 =
                ((unsigned long long)transScore(bV[s]) << 32) | (unsigned)bI[s];
            unsigned long long old1 = atomicMin(&L1[row], t1);
            unsigned long long cand = t1 < old1 ? old1 : t1;
            atomicMin(&L2s[row], (unsigned)(cand >> 32));
            atomicMin(&L2s[row], transScore(bT2[s]));
        }
    }
    __syncthreads();
    if (tid < BMt) {
        ulonglong2 v; v.x = L1[tid]; v.y = (unsigned long long)L2s[tid];
        tops[(rowBase + tid) * KSPLIT + blockIdx.y] = v;
    }
}

// merge + histogram of confidently-resolved rows
__global__ void merge_kernel(const ulonglong2* __restrict__ tops,
                             float* __restrict__ out, int* __restrict__ idxArr,
                             unsigned* __restrict__ flagCount,
                             int* __restrict__ flagRows, int* __restrict__ counts) {
    int row = blockIdx.x * 256 + threadIdx.x;
    ulonglong2 a = tops[row * 2], b = tops[row * 2 + 1];
    unsigned long long t1 = a.x < b.x ? a.x : b.x;
    unsigned a1 = (unsigned)(a.x >> 32), b1 = (unsigned)(b.x >> 32);
    unsigned mx = a1 > b1 ? a1 : b1;
    unsigned t2 = (unsigned)a.y < (unsigned)b.y ? (unsigned)a.y : (unsigned)b.y;
    t2 = t2 < mx ? t2 : mx;
    float s1 = untransScore((unsigned)(t1 >> 32));
    float s2 = untransScore(t2);
    int idx = (int)(t1 & 0xFFFFFFFFull);
    idxArr[row] = idx;
    out[IDX_OFF + row] = (float)idx;
    if (s2 - s1 <= DELTA) {
        unsigned p = atomicAdd(flagCount, 1u);
        flagRows[p] = row;
    } else {
        atomicAdd(&counts[idx], 1);
    }
}

// exact fp32 rescore of flagged rows. Grid = (RSL group slots, RKS K-splits).
__global__ __launch_bounds__(512) void resolve_kernel(
        const float* __restrict__ z, const float* __restrict__ cb,
        const float* __restrict__ c2, const unsigned* __restrict__ flagCount,
        const int* __restrict__ flagRows, unsigned long long* __restrict__ resolved) {
    __shared__ float zT[RDC][RBM + 4];
    __shared__ float cT[RDC][RBN + 4];
    __shared__ float c2s[RBN];
    __shared__ int rid[RBM];

    const int cnt = (int)*flagCount;
    const int tid = threadIdx.x;
    const int tx = tid & 31, ty = tid >> 5;
    const int rbase = ty * 8, cbase = tx * 4;
    const int k0 = blockIdx.y * (K / RKS);          // 256 codes per split

    for (int g = blockIdx.x; g * RBM < cnt; g += RSL) {
        __syncthreads();                // previous iteration fully done
        if (tid < RBM) {
            int fi = g * RBM + tid;
            rid[tid] = flagRows[fi < cnt ? fi : cnt - 1];   // pad = dup row (harmless)
        }

        float bestV[8]; int bestI[8];
#pragma unroll
        for (int r = 0; r < 8; ++r) { bestV[r] = 3.4e38f; bestI[r] = 0; }

        for (int kb = k0; kb < k0 + K / RKS; kb += RBN) {   // 2 iterations
            __syncthreads();            // prior score-phase reads of c2s done
            if (tid < RBN) c2s[tid] = c2[kb + tid];

            float acc[8][4];
#pragma unroll
            for (int r = 0; r < 8; ++r)
#pragma unroll
                for (int c = 0; c < 4; ++c) acc[r][c] = 0.f;

            for (int dc = 0; dc < D; dc += RDC) {
                __syncthreads();        // prior compute reads of zT/cT done
#pragma unroll
                for (int s = 0; s < 2; ++s) {
                    int f = tid + s * 512;          // 1024 float4 slots
                    int row = f >> 3, dq = f & 7;
                    float4 v = *(const float4*)(z + (long)rid[row] * D + dc + dq * 4);
                    zT[dq * 4 + 0][row] = v.x; zT[dq * 4 + 1][row] = v.y;
                    zT[dq * 4 + 2][row] = v.z; zT[dq * 4 + 3][row] = v.w;
                    float4 w = *(const float4*)(cb + (long)(kb + row) * D + dc + dq * 4);
                    cT[dq * 4 + 0][row] = w.x; cT[dq * 4 + 1][row] = w.y;
                    cT[dq * 4 + 2][row] = w.z; cT[dq * 4 + 3][row] = w.w;
                }
                __syncthreads();
#pragma unroll
                for (int d = 0; d < RDC; ++d) {
                    float a[8], b[4];
                    *(float4*)&a[0] = *(const float4*)&zT[d][rbase];
                    *(float4*)&a[4] = *(const float4*)&zT[d][rbase + 4];
                    *(float4*)&b[0] = *(const float4*)&cT[d][cbase];
#pragma unroll
                    for (int r = 0; r < 8; ++r)
#pragma unroll
                        for (int c = 0; c < 4; ++c)
                            acc[r][c] = fmaf(a[r], b[c], acc[r][c]);
                }
            }
            // score phase: c2 - 2*zc (z2 row-constant, argmin-invariant)
#pragma unroll
            for (int c = 0; c < 4; ++c) {
                float cc = c2s[cbase + c];
                int col = kb + cbase + c;
#pragma unroll
                for (int r = 0; r < 8; ++r) {
                    float score = fmaf(-2.f, acc[r][c], cc);
                    if (score < bestV[r]) { bestV[r] = score; bestI[r] = col; }
                }
            }
        }
        // reduce across the 32 tx-lanes sharing rows; first-index ties
#pragma unroll
        for (int off = 16; off; off >>= 1) {
#pragma unroll
            for (int r = 0; r < 8; ++r) {
                float ov = __shfl_xor(bestV[r], off);
                int   oi = __shfl_xor(bestI[r], off);
                if (ov < bestV[r] || (ov == bestV[r] && oi < bestI[r])) {
                    bestV[r] = ov; bestI[r] = oi;
                }
            }
        }
        if (tx == 0) {
#pragma unroll
            for (int r = 0; r < 8; ++r) {
                unsigned long long u =
                    ((unsigned long long)transScore(bestV[r]) << 32)
                    | (unsigned)bestI[r];
                atomicMin(&resolved[rid[rbase + r]], u);
            }
        }
    }
}

// writeback + histogram of flagged rows
__global__ void writeback_kernel(const unsigned* __restrict__ flagCount,
                                 const int* __restrict__ flagRows,
                                 const unsigned long long* __restrict__ resolved,
                                 int* __restrict__ idxArr, float* __restrict__ out,
                                 int* __restrict__ counts) {
    int i = blockIdx.x * 256 + threadIdx.x;
    if (i < (int)*flagCount) {
        int row = flagRows[i];
        int idx = (int)(resolved[row] & 0xFFFFFFFFull);
        idxArr[row] = idx;
        out[IDX_OFF + row] = (float)idx;
        atomicAdd(&counts[idx], 1);
    }
}

// single block: exclusive scan of counts -> cursor, CS output, n scalar
__global__ __launch_bounds__(1024) void scan_kernel(
        const int* __restrict__ counts, const float* __restrict__ cs,
        int* __restrict__ cursor, float* __restrict__ out,
        float* __restrict__ nacc) {
    __shared__ int wtot[16];
    __shared__ float csred[16];
    int tid = threadIdx.x;
    int lane = tid & 63, w = tid >> 6;
    int base = tid * 8;                 // 8192 / 1024
    int4 c0 = ((const int4*)(counts + base))[0];
    int4 c1 = ((const int4*)(counts + base))[1];
    float4 f0 = ((const float4*)(cs + base))[0];
    float4 f1 = ((const float4*)(cs + base))[1];
    int local[8] = {c0.x, c0.y, c0.z, c0.w, c1.x, c1.y, c1.z, c1.w};
    float csv[8] = {f0.x, f0.y, f0.z, f0.w, f1.x, f1.y, f1.z, f1.w};
    int sum = 0; float csum = 0.f;
#pragma unroll
    for (int i = 0; i < 8; ++i) { sum += local[i]; csum += csv[i]; }
    // wave-inclusive scan of per-thread sums
    int inc = sum;
#pragma unroll
    for (int off = 1; off < 64; off <<= 1) {
        int v = __shfl_up(inc, off);
        if (lane >= off) inc += v;
    }
    // cs partial reduce per wave
    for (int off = 32; off; off >>= 1) csum += __shfl_xor(csum, off);
    if (lane == 63) wtot[w] = inc;
    if (lane == 0) csred[w] = csum;
    __syncthreads();
    // wave 0 scans the 16 wave totals (exclusive)
    if (w == 0 && lane < 16) {
        int v = wtot[lane];
        int s2 = v;
#pragma unroll
        for (int off = 1; off < 16; off <<= 1) {
            int t = __shfl_up(s2, off);
            if (lane >= off) s2 += t;
        }
        wtot[lane] = s2 - v;            // exclusive wave offset
    }
    __syncthreads();
    int run = wtot[w] + (inc - sum);    // exclusive prefix of this thread chunk
#pragma unroll
    for (int i = 0; i < 8; ++i) {
        cursor[base + i] = run;
        out[CS_OFF + base + i] = csv[i] * DECAY + OMD * (float)local[i];
        run += local[i];
    }
    if (tid == 0) {
        float t = 0.f;
#pragma unroll
        for (int i = 0; i < 16; ++i) t += csred[i];
        *nacc = t * DECAY + OMD * (float)N;   // sum(counts) == N exactly
    }
}

__global__ void scatter_kernel(const int* __restrict__ idxArr,
                               int* __restrict__ cursor, int* __restrict__ sorted) {
    int row = blockIdx.x * 256 + threadIdx.x;
    int pos = atomicAdd(&cursor[idxArr[row]], 1);
    sorted[pos] = row;
}

// one wave per code: gather-sum its rows, write new_embedding_avg AND
// new_codebook (finalize folded in; nacc/cs ready since scan precedes).
__global__ __launch_bounds__(256) void gather_sum_kernel(
        const float* __restrict__ z, const float* __restrict__ emb,
        const int* __restrict__ sorted, const int* __restrict__ cursor,
        const int* __restrict__ counts, const float* __restrict__ nacc,
        float* __restrict__ out) {
    int k = blockIdx.x * 4 + (threadIdx.x >> 6);
    int lane = threadIdx.x & 63;
    int cnt = counts[k];
    int start = cursor[k] - cnt;        // cursor was advanced by scatter
    float4 s = {0.f, 0.f, 0.f, 0.f};
    for (int i = 0; i < cnt; ++i) {
        int row = sorted[start + i];
        float4 v = *(const float4*)(z + (long)row * D + lane * 4);
        s.x += v.x; s.y += v.y; s.z += v.z; s.w += v.w;
    }
    float4 e = *(const float4*)(emb + (long)k * D + lane * 4);
    float4 o;
    o.x = e.x * DECAY + OMD * s.x;
    o.y = e.y * DECAY + OMD * s.y;
    o.z = e.z * DECAY + OMD * s.z;
    o.w = e.w * DECAY + OMD * s.w;
    *(float4*)(out + EMB_OFF + (long)k * D + lane * 4) = o;
    float n = *nacc;
    float ncs = out[CS_OFF + k];
    float smoothed = (ncs + EPS) / (n + (float)K * EPS) * n;
    float4 q;
    q.x = o.x / smoothed; q.y = o.y / smoothed;
    q.z = o.z / smoothed; q.w = o.w / smoothed;
    *(float4*)(out + CB_OFF + (long)k * D + lane * 4) = q;
}

__global__ __launch_bounds__(512) void quantize_kernel(
        const float* __restrict__ cb, const int* __restrict__ idxArr,
        float* __restrict__ out) {
    int tid = threadIdx.x;
    int r = tid >> 2, seg = tid & 3;
    int gRow = blockIdx.x * 128 + r;
    int code = idxArr[gRow];
    const float4* cbv = (const float4*)(cb + (long)code * D + seg * 64);
    float4* qv = (float4*)(out + Q_OFF + (long)gRow * D + seg * 64);
#pragma unroll 4
    for (int i = 0; i < 16; ++i) qv[i] = cbv[i];
}

extern "C" void kernel_launch(void* const* d_in, const int* in_sizes, int n_in,
                              void* d_out, int out_size, void* d_ws, size_t ws_size,
                              hipStream_t stream) {
    const float* z   = (const float*)d_in[0];
    const float* cb  = (const float*)d_in[1];
    const float* emb = (const float*)d_in[2];
    const float* cs  = (const float*)d_in[3];
    float* out = (float*)d_out;
    char* ws = (char*)d_ws;

    ulonglong2* tops = (ulonglong2*)(ws + WS_TOPS);
    unsigned long long* resolved = (unsigned long long*)(ws + WS_RES);
    int* idxArr = (int*)(ws + WS_IDX);
    float* c2 = (float*)(ws + WS_C2);
    int* flagRows = (int*)(ws + WS_FLAG);
    unsigned* flagCount = (unsigned*)(ws + WS_CNT);
    float* nacc = (float*)(ws + WS_CNT) + 1;
    int* counts = (int*)(ws + WS_CNTS);
    int* cursor = (int*)(ws + WS_CUR);
    int* sorted = (int*)(ws + WS_SORT);
    _Float16* cb16 = (_Float16*)(out + Q_OFF);   // scratch in quantized region

    prep_kernel<<<K, 64, 0, stream>>>(cb, cb16, c2, ws);
    dim3 ggrid(N / BMt, KSPLIT);
    gemm_kernel<<<ggrid, GT, 0, stream>>>(z, cb16, c2, tops);
    merge_kernel<<<N / 256, 256, 0, stream>>>(tops, out, idxArr, flagCount,
                                              flagRows, counts);
    dim3 rgrid(RSL, RKS);
    resolve_kernel<<<rgrid, 512, 0, stream>>>(z, cb, c2, flagCount, flagRows, resolved);
    writeback_kernel<<<N / 256, 256, 0, stream>>>(flagCount, flagRows, resolved,
                                                  idxArr, out, counts);
    scan_kernel<<<1, 1024, 0, stream>>>(counts, cs, cursor, out, nacc);
    scatter_kernel<<<N / 256, 256, 0, stream>>>(idxArr, cursor, sorted);
    gather_sum_kernel<<<K / 4, 256, 0, stream>>>(z, emb, sorted, cursor, counts,
                                                 nacc, out);
    quantize_kernel<<<N / 128, 512, 0, stream>>>(cb, idxArr, out);
}